// Round 14
// baseline (243.128 us; speedup 1.0000x reference)
//
#include <hip/hip_runtime.h>

// ---------------- problem constants ----------------
constexpr int BATCH = 4;
constexpr int HS    = 64;     // H
constexpr int WSZ   = 64;     // W
constexpr int LSEQ  = 4096;   // L = H*W
constexpr int DM    = 96;     // d_model
constexpr int DI    = 192;    // d_inner
constexpr int NS    = 16;     // d_state
constexpr int RK    = 6;      // dt_rank
constexpr int KD    = 4;      // scan directions
constexpr int NCH   = 128;    // chunks along L
constexpr int CLEN  = 32;     // chunk length
constexpr int XDS   = 160;    // packed xdbl row: 4 * [B(16) C(16) dt(6) pad(2)]
constexpr int GCH   = 16;     // combine groups
constexpr int GLEN  = NCH / GCH;  // 8 chunks per group

// scan index l -> spatial position p (row-major h*64+w), per direction
__device__ __forceinline__ int pos_of(int k, int l) {
  switch (k & 3) {
    case 0: return l;
    case 1: return ((l & 63) << 6) | (l >> 6);
    case 2: return LSEQ - 1 - l;
    default: { int lp = LSEQ - 1 - l; return ((lp & 63) << 6) | (lp >> 6); }
  }
}

__device__ __forceinline__ float softplus_f(float s) {
  return (s > 20.f) ? s : __logf(1.f + __expf(s));
}

// powers e^(off+1) .. e^(off+8) where off = half*8, via base = half ? e^8 : 1
__device__ __forceinline__ void pw8h(float e, float base, float* p) {
  float e2 = e * e, e4 = e2 * e2;
  float e3 = e2 * e, e5 = e4 * e, e6 = e4 * e2, e7 = e6 * e, e8 = e4 * e4;
  p[0] = base * e;  p[1] = base * e2; p[2] = base * e3; p[3] = base * e4;
  p[4] = base * e5; p[5] = base * e6; p[6] = base * e7; p[7] = base * e8;
}

// geo check on A_logs directly: Alog[n] == Alog[0] + ln(n+1)
__device__ __forceinline__ bool geo_check(const float* Al) {
  const float lntab[16] = {0.f, 0.6931472f, 1.0986123f, 1.3862944f, 1.6094379f,
                           1.7917595f, 1.9459101f, 2.0794415f, 2.1972246f, 2.3025851f,
                           2.3978953f, 2.4849066f, 2.5649494f, 2.6390573f, 2.7080502f,
                           2.7725887f};
  bool g = true;
  #pragma unroll
  for (int n = 0; n < NS; ++n)
    g = g && (fabsf(Al[n] - Al[0] - lntab[n]) <= 2e-3f);
  return g;
}

__device__ __forceinline__ float dt6(const float* w, float bsv, float4 t0, float4 t1) {
  return bsv + w[0]*t0.x + w[1]*t0.y + w[2]*t0.z + w[3]*t0.w + w[4]*t1.x + w[5]*t1.y;
}

// ---------------- merged weight prep: WcatT[192][160], inpT[96][384], outpT[192][96]
__launch_bounds__(256)
__global__ void prep_weights(const float* __restrict__ xw, const float* __restrict__ ipw,
                             const float* __restrict__ opw, float* __restrict__ WcatT,
                             float* __restrict__ inpT, float* __restrict__ outpT) {
  int idx = blockIdx.x * 256 + threadIdx.x;
  if (idx < DI * XDS) {                          // WcatT
    int col = idx / XDS, j = idx % XDS;
    int k = j / 40, jj = j % 40;
    float v = 0.f;
    int src = -1;
    if (jj < 16)      src = k * 38 + 6 + jj;
    else if (jj < 32) src = k * 38 + 22 + (jj - 16);
    else if (jj < 38) src = k * 38 + (jj - 32);
    if (src >= 0) v = xw[(size_t)src * DI + col];
    WcatT[idx] = v;
    return;
  }
  idx -= DI * XDS;
  if (idx < 2 * DI * DM) {                       // inpT[c][r] = ipw[r][c]
    int r = idx / DM, c = idx % DM;
    inpT[(size_t)c * (2 * DI) + r] = ipw[idx];
    return;
  }
  idx -= 2 * DI * DM;
  if (idx < DM * DI) {                           // outpT[c][r] = opw[r][c]
    int r = idx / DI, c = idx % DI;
    outpT[(size_t)c * DM + r] = opw[idx];
  }
}

// ---------------- GEMM: C[M,NN] = A[M,KK] * BT[KK,NN]   (BT pre-transposed) ------
template <int NN, int KK, int TM, int KT>
__launch_bounds__(256)
__global__ void gemm_nt(const float* __restrict__ A, const float* __restrict__ BT,
                        float* __restrict__ C, int M) {
  constexpr int TN  = 64;
  constexpr int RPT = TM / 16;
  constexpr int SA  = KT + 4;
  constexpr int KQ  = KT / 4;
  __shared__ float As[TM][SA];
  __shared__ float Bs[KT][TN];
  const int t = threadIdx.x;
  const int row0 = blockIdx.y * TM;
  const int col0 = blockIdx.x * TN;
  const int tc = t & 15;
  const int tr = t >> 4;

  float acc[RPT][4];
  #pragma unroll
  for (int i = 0; i < RPT; ++i)
    { acc[i][0]=0.f; acc[i][1]=0.f; acc[i][2]=0.f; acc[i][3]=0.f; }

  for (int k0 = 0; k0 < KK; k0 += KT) {
    #pragma unroll 1
    for (int idx = t; idx < TM * KQ; idx += 256) {
      int r = idx / KQ, kq = idx % KQ;
      *(float4*)&As[r][kq * 4] =
          *(const float4*)&A[(size_t)(row0 + r) * KK + k0 + kq * 4];
    }
    #pragma unroll 1
    for (int idx = t; idx < KT * 16; idx += 256) {
      int kk = idx >> 4, cq = idx & 15;
      int col = col0 + cq * 4;
      float4 v = make_float4(0.f, 0.f, 0.f, 0.f);
      if (col < NN) v = *(const float4*)&BT[(size_t)(k0 + kk) * NN + col];
      *(float4*)&Bs[kk][cq * 4] = v;
    }
    __syncthreads();
    #pragma unroll 4
    for (int kk = 0; kk < KT; ++kk) {
      float4 bv = *(const float4*)&Bs[kk][tc * 4];
      #pragma unroll
      for (int i = 0; i < RPT; ++i) {
        float a = As[tr * RPT + i][kk];
        acc[i][0] += a * bv.x; acc[i][1] += a * bv.y;
        acc[i][2] += a * bv.z; acc[i][3] += a * bv.w;
      }
    }
    __syncthreads();
  }
  int c = col0 + tc * 4;
  if (c < NN) {
    #pragma unroll
    for (int i = 0; i < RPT; ++i) {
      size_t r0 = (size_t)(row0 + tr * RPT + i) * NN + c;
      *(float4*)&C[r0] = make_float4(acc[i][0], acc[i][1], acc[i][2], acc[i][3]);
    }
  }
}

// ---------------- depthwise 3x3 conv + bias + SiLU ----------------
__launch_bounds__(256)
__global__ void conv_silu(const float* __restrict__ xz, const float* __restrict__ cw,
                          const float* __restrict__ cb, float* __restrict__ xc) {
  int idx = blockIdx.x * 256 + threadIdx.x;
  int d = idx % DI;
  int p = (idx / DI) % LSEQ;
  int b = idx / (DI * LSEQ);
  int h = p >> 6, w = p & 63;
  float acc = cb[d];
  #pragma unroll
  for (int kh = 0; kh < 3; ++kh) {
    int hh = h + kh - 1;
    if ((unsigned)hh >= (unsigned)HS) continue;
    #pragma unroll
    for (int kw = 0; kw < 3; ++kw) {
      int ww = w + kw - 1;
      if ((unsigned)ww >= (unsigned)WSZ) continue;
      acc += xz[((size_t)b * LSEQ + (hh << 6) + ww) * (2 * DI) + d] * cw[d * 9 + kh * 3 + kw];
    }
  }
  xc[idx] = acc / (1.f + __expf(-acc));
}

// ---- scan phase 1 (n-split x2): local scan + y_loc -> plane; hN + sumd ----------
// 384 threads: d = t>>1, half = t&1; each thread owns 8 states.
__launch_bounds__(384)
__global__ void scan_phase1(const float* __restrict__ xc, const float* __restrict__ xdbl,
                            const float* __restrict__ Alog, const float* __restrict__ dtw,
                            const float* __restrict__ dtb,
                            float* __restrict__ hN, float* __restrict__ sumdB,
                            float* __restrict__ ypl) {
  const int t = threadIdx.x;
  const int d = t >> 1, half = t & 1;
  const int ch = blockIdx.x, k = blockIdx.y, b = blockIdx.z;
  const int bk = b * KD + k;
  __shared__ float4 Bsh[CLEN * 10];         // per pos: B(0..3) C(4..7) dt(8,9)
  if (t < CLEN * 10) {
    int j = t / 10, q = t % 10;
    int p = pos_of(k, ch * CLEN + j);
    Bsh[t] = *(const float4*)&xdbl[(size_t)(b * LSEQ + p) * XDS + k * 40 + q * 4];
  }
  float Al[NS];
  {
    const float4* Ap = (const float4*)&Alog[((size_t)k * DI + d) * NS];
    #pragma unroll
    for (int q = 0; q < 4; ++q) {
      float4 a = Ap[q];
      Al[q*4+0] = a.x; Al[q*4+1] = a.y; Al[q*4+2] = a.z; Al[q*4+3] = a.w;
    }
  }
  const bool geo = geo_check(Al);
  const float An0 = -__expf(Al[0]);
  float w[RK];
  #pragma unroll
  for (int r = 0; r < RK; ++r) w[r] = dtw[((size_t)k * DI + d) * RK + r];
  const float bsv = dtb[k * DI + d];
  __syncthreads();

  float h[8];
  #pragma unroll
  for (int n = 0; n < 8; ++n) h[n] = 0.f;
  float sumd = 0.f;
  float* yout = ypl + (size_t)bk * LSEQ * DI;
  const int l0 = ch * CLEN;
  const int hb = half * 2;                  // float4 offset for this half's B/C
  if (geo) {
    #pragma unroll 2
    for (int j = 0; j < CLEN; ++j) {
      const int p = pos_of(k, l0 + j);
      const size_t bp = (size_t)b * LSEQ + p;
      float4 t0 = Bsh[j * 10 + 8], t1 = Bsh[j * 10 + 9];
      float dl = softplus_f(dt6(w, bsv, t0, t1));
      float du = dl * xc[bp * DI + d];
      float e = __expf(dl * An0);
      float e2 = e * e, e4 = e2 * e2, e8 = e4 * e4;
      float base = half ? e8 : 1.f;
      float pw[8];
      pw8h(e, base, pw);
      float4 v0 = Bsh[j * 10 + hb],     v1 = Bsh[j * 10 + hb + 1];
      float4 c0 = Bsh[j * 10 + 4 + hb], c1 = Bsh[j * 10 + 4 + hb + 1];
      float y = 0.f;
      h[0] = pw[0] * h[0] + du * v0.x; y += h[0] * c0.x;
      h[1] = pw[1] * h[1] + du * v0.y; y += h[1] * c0.y;
      h[2] = pw[2] * h[2] + du * v0.z; y += h[2] * c0.z;
      h[3] = pw[3] * h[3] + du * v0.w; y += h[3] * c0.w;
      h[4] = pw[4] * h[4] + du * v1.x; y += h[4] * c1.x;
      h[5] = pw[5] * h[5] + du * v1.y; y += h[5] * c1.y;
      h[6] = pw[6] * h[6] + du * v1.z; y += h[6] * c1.z;
      h[7] = pw[7] * h[7] + du * v1.w; y += h[7] * c1.w;
      y += __shfl_xor(y, 1);
      sumd += dl;
      if (!half) yout[(size_t)p * DI + d] = y;
    }
  } else {
    float An[8];
    #pragma unroll
    for (int n = 0; n < 8; ++n) An[n] = -__expf(Al[half * 8 + n]);
    #pragma unroll 1
    for (int j = 0; j < CLEN; ++j) {
      const int p = pos_of(k, l0 + j);
      const size_t bp = (size_t)b * LSEQ + p;
      float4 t0 = Bsh[j * 10 + 8], t1 = Bsh[j * 10 + 9];
      float dl = softplus_f(dt6(w, bsv, t0, t1));
      float du = dl * xc[bp * DI + d];
      float4 v0 = Bsh[j * 10 + hb],     v1 = Bsh[j * 10 + hb + 1];
      float4 c0 = Bsh[j * 10 + 4 + hb], c1 = Bsh[j * 10 + 4 + hb + 1];
      float y = 0.f;
      h[0] = __expf(dl*An[0]) * h[0] + du * v0.x; y += h[0] * c0.x;
      h[1] = __expf(dl*An[1]) * h[1] + du * v0.y; y += h[1] * c0.y;
      h[2] = __expf(dl*An[2]) * h[2] + du * v0.z; y += h[2] * c0.z;
      h[3] = __expf(dl*An[3]) * h[3] + du * v0.w; y += h[3] * c0.w;
      h[4] = __expf(dl*An[4]) * h[4] + du * v1.x; y += h[4] * c1.x;
      h[5] = __expf(dl*An[5]) * h[5] + du * v1.y; y += h[5] * c1.y;
      h[6] = __expf(dl*An[6]) * h[6] + du * v1.z; y += h[6] * c1.z;
      h[7] = __expf(dl*An[7]) * h[7] + du * v1.w; y += h[7] * c1.w;
      y += __shfl_xor(y, 1);
      sumd += dl;
      if (!half) yout[(size_t)p * DI + d] = y;
    }
  }
  const size_t o = ((size_t)bk * NCH + ch) * DI + d;
  float4* Hp = (float4*)&hN[o * NS];
  Hp[half * 2 + 0] = make_float4(h[0], h[1], h[2], h[3]);
  Hp[half * 2 + 1] = make_float4(h[4], h[5], h[6], h[7]);
  if (!half) sumdB[o] = sumd;
}

// ---- hierarchical combine: level A — per-group aggregates (W, T) ---------------
__launch_bounds__(256)
__global__ void combine_a(const float* __restrict__ hN, const float* __restrict__ sumdB,
                          const float* __restrict__ Alog,
                          float* __restrict__ Wg, float* __restrict__ Tg) {
  const int tid = blockIdx.x * 256 + threadIdx.x;
  const int n  = tid & 15;
  int rem = tid >> 4;
  const int d  = rem % DI;  rem /= DI;
  const int g  = rem % GCH;
  const int bk = rem / GCH;
  const int k  = bk & 3;
  const float An = -__expf(Alog[((size_t)k * DI + d) * NS + n]);
  float W = 1.f, T = 0.f;
  #pragma unroll
  for (int j = 0; j < GLEN; ++j) {
    const int c = g * GLEN + j;
    const size_t o = ((size_t)bk * NCH + c) * DI + d;
    float w = __expf(An * sumdB[o]);
    T = hN[o * NS + n] + w * T;
    W *= w;
  }
  Wg[tid] = W;
  Tg[tid] = T;
}

// ---- level B — serial scan over the GCH group aggregates -> group entry Hg -----
__launch_bounds__(256)
__global__ void combine_b(const float* __restrict__ Wg, const float* __restrict__ Tg,
                          float* __restrict__ Hg) {
  const int tid = blockIdx.x * 256 + threadIdx.x;    // over B*K*D*N
  const int dn = tid & (DI * NS - 1);
  const int bk = tid / (DI * NS);
  float H = 0.f;
  #pragma unroll
  for (int g = 0; g < GCH; ++g) {
    const size_t o = ((size_t)(bk * GCH + g)) * (DI * NS) + dn;
    Hg[o] = H;
    H = Tg[o] + Wg[o] * H;
  }
}

// ---- level C — re-walk group, write per-chunk entry states into hN (in place) --
__launch_bounds__(256)
__global__ void combine_c(float* __restrict__ hN, const float* __restrict__ sumdB,
                          const float* __restrict__ Alog, const float* __restrict__ Hg) {
  const int tid = blockIdx.x * 256 + threadIdx.x;
  const int n  = tid & 15;
  int rem = tid >> 4;
  const int d  = rem % DI;  rem /= DI;
  const int g  = rem % GCH;
  const int bk = rem / GCH;
  const int k  = bk & 3;
  const float An = -__expf(Alog[((size_t)k * DI + d) * NS + n]);
  float e = Hg[tid];
  #pragma unroll
  for (int j = 0; j < GLEN; ++j) {
    const int c = g * GLEN + j;
    const size_t o = ((size_t)bk * NCH + c) * DI + d;
    float w = __expf(An * sumdB[o]);
    float tmp = hN[o * NS + n];
    hN[o * NS + n] = e;
    e = tmp + w * e;
  }
}

// ---- scan correction (n-split x2): ypl[p] += C . (h0 * exp(An*cum)) ------------
__launch_bounds__(384)
__global__ void scan_corr(const float* __restrict__ xdbl, const float* __restrict__ Alog,
                          const float* __restrict__ dtw, const float* __restrict__ dtb,
                          const float* __restrict__ hin, float* __restrict__ ypl) {
  const int t = threadIdx.x;
  const int d = t >> 1, half = t & 1;
  const int ch = blockIdx.x + 1;            // ch=0 has zero entry state
  const int k = blockIdx.y, b = blockIdx.z;
  const int bk = b * KD + k;
  __shared__ float4 Bsh[CLEN * 6];          // per pos: C(q4..7) dt(q8,q9)
  if (t < CLEN * 6) {
    int j = t / 6, q = t % 6;
    int p = pos_of(k, ch * CLEN + j);
    Bsh[t] = *(const float4*)&xdbl[(size_t)(b * LSEQ + p) * XDS + k * 40 + (q + 4) * 4];
  }
  float Al[NS];
  {
    const float4* Ap = (const float4*)&Alog[((size_t)k * DI + d) * NS];
    #pragma unroll
    for (int q = 0; q < 4; ++q) {
      float4 a = Ap[q];
      Al[q*4+0] = a.x; Al[q*4+1] = a.y; Al[q*4+2] = a.z; Al[q*4+3] = a.w;
    }
  }
  const bool geo = geo_check(Al);
  const float An0 = -__expf(Al[0]);
  float w[RK];
  #pragma unroll
  for (int r = 0; r < RK; ++r) w[r] = dtw[((size_t)k * DI + d) * RK + r];
  const float bsv = dtb[k * DI + d];

  float g[8];                               // this half's entry state
  {
    const size_t o = ((size_t)bk * NCH + ch) * DI + d;
    const float4* Hp = (const float4*)&hin[o * NS];
    float4 v = Hp[half * 2 + 0];
    g[0]=v.x; g[1]=v.y; g[2]=v.z; g[3]=v.w;
    float4 u = Hp[half * 2 + 1];
    g[4]=u.x; g[5]=u.y; g[6]=u.z; g[7]=u.w;
  }
  __syncthreads();
  float* yout = ypl + (size_t)bk * LSEQ * DI;
  const int l0 = ch * CLEN;
  const int hb = half * 2;
  float cum = 0.f;
  if (geo) {
    #pragma unroll 2
    for (int j = 0; j < CLEN; ++j) {
      const int p = pos_of(k, l0 + j);
      float4 t0 = Bsh[j * 6 + 4], t1 = Bsh[j * 6 + 5];
      cum += softplus_f(dt6(w, bsv, t0, t1));
      float e = __expf(cum * An0);
      float e2 = e * e, e4 = e2 * e2, e8 = e4 * e4;
      float base = half ? e8 : 1.f;
      float pw[8];
      pw8h(e, base, pw);
      float4 c0 = Bsh[j * 6 + hb], c1 = Bsh[j * 6 + hb + 1];
      float y = 0.f;
      y += (pw[0] * g[0]) * c0.x; y += (pw[1] * g[1]) * c0.y;
      y += (pw[2] * g[2]) * c0.z; y += (pw[3] * g[3]) * c0.w;
      y += (pw[4] * g[4]) * c1.x; y += (pw[5] * g[5]) * c1.y;
      y += (pw[6] * g[6]) * c1.z; y += (pw[7] * g[7]) * c1.w;
      y += __shfl_xor(y, 1);
      if (!half) yout[(size_t)p * DI + d] += y;
    }
  } else {
    float An[8];
    #pragma unroll
    for (int n = 0; n < 8; ++n) An[n] = -__expf(Al[half * 8 + n]);
    #pragma unroll 1
    for (int j = 0; j < CLEN; ++j) {
      const int p = pos_of(k, l0 + j);
      float4 t0 = Bsh[j * 6 + 4], t1 = Bsh[j * 6 + 5];
      cum += softplus_f(dt6(w, bsv, t0, t1));
      float4 c0 = Bsh[j * 6 + hb], c1 = Bsh[j * 6 + hb + 1];
      float y = 0.f;
      y += (__expf(An[0] * cum) * g[0]) * c0.x;
      y += (__expf(An[1] * cum) * g[1]) * c0.y;
      y += (__expf(An[2] * cum) * g[2]) * c0.z;
      y += (__expf(An[3] * cum) * g[3]) * c0.w;
      y += (__expf(An[4] * cum) * g[4]) * c1.x;
      y += (__expf(An[5] * cum) * g[5]) * c1.y;
      y += (__expf(An[6] * cum) * g[6]) * c1.z;
      y += (__expf(An[7] * cum) * g[7]) * c1.w;
      y += __shfl_xor(y, 1);
      if (!half) yout[(size_t)p * DI + d] += y;
    }
  }
}

// -------- 4-plane merge (Ds term) + LayerNorm + SiLU gate ----------------
__launch_bounds__(192)
__global__ void fuse_ln(const float* __restrict__ ypl, const float* __restrict__ xc,
                        const float* __restrict__ Ds, const float* __restrict__ xz,
                        const float* __restrict__ lnw, const float* __restrict__ lnb,
                        float* __restrict__ ymul) {
  const int row = blockIdx.x;           // b*L + p
  const int b = row >> 12;
  const size_t pd = (size_t)row * DI + threadIdx.x;
  const int d = threadIdx.x;
  constexpr size_t PL = (size_t)LSEQ * DI;
  float u = xc[pd];
  float sDs = Ds[d] + Ds[DI + d] + Ds[2 * DI + d] + Ds[3 * DI + d];
  const size_t base = (size_t)(b * KD) * PL + pd - (size_t)b * PL;
  float y = ypl[base] + ypl[base + PL] + ypl[base + 2 * PL] + ypl[base + 3 * PL] + sDs * u;
  float s1 = y, s2 = y * y;
  #pragma unroll
  for (int off = 32; off; off >>= 1) {
    s1 += __shfl_xor(s1, off);
    s2 += __shfl_xor(s2, off);
  }
  __shared__ float r1[3], r2[3];
  int wid = d >> 6;
  if ((d & 63) == 0) { r1[wid] = s1; r2[wid] = s2; }
  __syncthreads();
  float S1 = r1[0] + r1[1] + r1[2];
  float S2 = r2[0] + r2[1] + r2[2];
  float mu = S1 * (1.f / DI);
  float var = S2 * (1.f / DI) - mu * mu;
  float yn = (y - mu) * rsqrtf(var + 1e-5f) * lnw[d] + lnb[d];
  float zv = xz[(size_t)row * (2 * DI) + DI + d];
  float g = zv / (1.f + __expf(-zv));
  ymul[pd] = yn * g;
}

// ---------------- launcher ----------------
extern "C" void kernel_launch(void* const* d_in, const int* in_sizes, int n_in,
                              void* d_out, int out_size, void* d_ws, size_t ws_size,
                              hipStream_t stream) {
  (void)in_sizes; (void)n_in; (void)out_size; (void)ws_size;
  const float* x          = (const float*)d_in[0];
  const float* in_proj_w  = (const float*)d_in[1];
  const float* conv_w     = (const float*)d_in[2];
  const float* conv_b     = (const float*)d_in[3];
  const float* x_proj_w   = (const float*)d_in[4];
  const float* dt_w       = (const float*)d_in[5];
  const float* dt_b       = (const float*)d_in[6];
  const float* A_logs     = (const float*)d_in[7];
  const float* Ds         = (const float*)d_in[8];
  const float* ln_w       = (const float*)d_in[9];
  const float* ln_b       = (const float*)d_in[10];
  const float* out_proj_w = (const float*)d_in[11];
  float* out = (float*)d_out;
  float* ws  = (float*)d_ws;

  constexpr size_t SZ_XZ    = (size_t)BATCH * LSEQ * 2 * DI;
  constexpr size_t SZ_XC    = (size_t)BATCH * LSEQ * DI;
  constexpr size_t SZ_XD    = (size_t)BATCH * LSEQ * XDS;
  constexpr size_t SZ_HN    = (size_t)BATCH * KD * NCH * DI * NS;   // 25 MB
  constexpr size_t SZ_SUMD  = (size_t)BATCH * KD * NCH * DI;
  constexpr size_t SZ_YPL   = (size_t)BATCH * KD * LSEQ * DI;
  constexpr size_t SZ_G     = (size_t)BATCH * KD * GCH * DI * NS;

  float* xz    = ws;
  float* xc    = xz + SZ_XZ;
  float* xdbl  = xc + SZ_XC;
  float* hN    = xdbl + SZ_XD;
  float* sumd  = hN + SZ_HN;
  float* ypl   = sumd + SZ_SUMD;
  float* WcatT = ypl + SZ_YPL;
  float* inpT  = WcatT + (size_t)DI * XDS;
  float* outpT = inpT + (size_t)DM * 2 * DI;
  float* Wg    = outpT + (size_t)DI * DM;
  float* Tg    = Wg + SZ_G;
  float* Hg    = Tg + SZ_G;
  float* ymul  = hN;    // hN dead after scan_corr; reuse for LN output

  const int M = BATCH * LSEQ;  // 16384
  const int SG = BATCH * KD * GCH * DI * NS;   // combine_a/c threads
  const int PREP = DI * XDS + 2 * DI * DM + DM * DI;

  // 0. weight prep (merged)
  prep_weights<<<(PREP + 255) / 256, 256, 0, stream>>>(x_proj_w, in_proj_w, out_proj_w,
                                                       WcatT, inpT, outpT);
  // 1. in_proj
  gemm_nt<2 * DI, DM, 64, 96><<<dim3(6, M / 64), 256, 0, stream>>>(x, inpT, xz, M);
  // 2. depthwise conv + SiLU -> xc
  conv_silu<<<(BATCH * LSEQ * DI) / 256, 256, 0, stream>>>(xz, conv_w, conv_b, xc);
  // 3. x_proj all directions: xdbl[M,160]
  gemm_nt<XDS, DI, 64, 96><<<dim3(3, M / 64), 256, 0, stream>>>(xc, WcatT, xdbl, M);
  // 4. scan phase 1 (n-split): local scan + y_loc -> planes
  scan_phase1<<<dim3(NCH, KD, BATCH), 384, 0, stream>>>(xc, xdbl, A_logs, dt_w, dt_b,
                                                        hN, sumd, ypl);
  // 5. hierarchical chunk combine (hN -> entry states, in place)
  combine_a<<<SG / 256, 256, 0, stream>>>(hN, sumd, A_logs, Wg, Tg);
  combine_b<<<(BATCH * KD * DI * NS) / 256, 256, 0, stream>>>(Wg, Tg, Hg);
  combine_c<<<SG / 256, 256, 0, stream>>>(hN, sumd, A_logs, Hg);
  // 6. correction (n-split): ypl += C . (h0 * exp(An*cumDelta))
  scan_corr<<<dim3(NCH - 1, KD, BATCH), 384, 0, stream>>>(xdbl, A_logs, dt_w, dt_b,
                                                          hN, ypl);
  // 7. merge 4 planes + LN + gate -> ymul (aliases hN)
  fuse_ln<<<M, DI, 0, stream>>>(ypl, xc, Ds, xz, ln_w, ln_b, ymul);
  // 8. out_proj
  gemm_nt<DM, DI, 64, 96><<<dim3(2, M / 64), 256, 0, stream>>>(ymul, outpT, out, M);
}

// Round 15
// 218.509 us; speedup vs baseline: 1.1127x; 1.1127x over previous
//
#include <hip/hip_runtime.h>

// ---------------- problem constants ----------------
constexpr int BATCH = 4;
constexpr int HS    = 64;     // H
constexpr int WSZ   = 64;     // W
constexpr int LSEQ  = 4096;   // L = H*W
constexpr int DM    = 96;     // d_model
constexpr int DI    = 192;    // d_inner
constexpr int NS    = 16;     // d_state
constexpr int RK    = 6;      // dt_rank
constexpr int KD    = 4;      // scan directions
constexpr int NCH   = 128;    // chunks along L
constexpr int CLEN  = 32;     // chunk length
constexpr int XDS   = 160;    // packed xdbl row: 4 * [B(16) C(16) dt(6) pad(2)]
constexpr int GCH   = 16;     // combine groups
constexpr int GLEN  = NCH / GCH;  // 8 chunks per group

// scan index l -> spatial position p (row-major h*64+w), per direction
__device__ __forceinline__ int pos_of(int k, int l) {
  switch (k & 3) {
    case 0: return l;
    case 1: return ((l & 63) << 6) | (l >> 6);
    case 2: return LSEQ - 1 - l;
    default: { int lp = LSEQ - 1 - l; return ((lp & 63) << 6) | (lp >> 6); }
  }
}

__device__ __forceinline__ float softplus_f(float s) {
  return (s > 20.f) ? s : __logf(1.f + __expf(s));
}

// log-depth powers: p[i] = e^i for i=1..16 (depth <= 4, 15 muls)
__device__ __forceinline__ void pw16(float e, float* p) {
  float e2 = e * e, e4 = e2 * e2, e8 = e4 * e4;
  p[1] = e;       p[2] = e2;      p[3] = e2 * e;  p[4] = e4;
  p[5] = e4 * e;  p[6] = e4 * e2; p[7] = p[6] * e; p[8] = e8;
  p[9] = e8 * e;  p[10] = e8 * e2; p[11] = p[10] * e; p[12] = e8 * e4;
  p[13] = p[12] * e; p[14] = p[12] * e2; p[15] = p[14] * e; p[16] = e8 * e8;
}

// geo check on A_logs directly: Alog[n] == Alog[0] + ln(n+1)
__device__ __forceinline__ bool geo_check(const float* Al) {
  const float lntab[16] = {0.f, 0.6931472f, 1.0986123f, 1.3862944f, 1.6094379f,
                           1.7917595f, 1.9459101f, 2.0794415f, 2.1972246f, 2.3025851f,
                           2.3978953f, 2.4849066f, 2.5649494f, 2.6390573f, 2.7080502f,
                           2.7725887f};
  bool g = true;
  #pragma unroll
  for (int n = 0; n < NS; ++n)
    g = g && (fabsf(Al[n] - Al[0] - lntab[n]) <= 2e-3f);
  return g;
}

__device__ __forceinline__ float dt6(const float* w, float bsv, float4 t0, float4 t1) {
  return bsv + w[0]*t0.x + w[1]*t0.y + w[2]*t0.z + w[3]*t0.w + w[4]*t1.x + w[5]*t1.y;
}

// ---------------- merged weight prep: WcatT[192][160], inpT[96][384], outpT[192][96]
__launch_bounds__(256)
__global__ void prep_weights(const float* __restrict__ xw, const float* __restrict__ ipw,
                             const float* __restrict__ opw, float* __restrict__ WcatT,
                             float* __restrict__ inpT, float* __restrict__ outpT) {
  int idx = blockIdx.x * 256 + threadIdx.x;
  if (idx < DI * XDS) {                          // WcatT
    int col = idx / XDS, j = idx % XDS;
    int k = j / 40, jj = j % 40;
    float v = 0.f;
    int src = -1;
    if (jj < 16)      src = k * 38 + 6 + jj;
    else if (jj < 32) src = k * 38 + 22 + (jj - 16);
    else if (jj < 38) src = k * 38 + (jj - 32);
    if (src >= 0) v = xw[(size_t)src * DI + col];
    WcatT[idx] = v;
    return;
  }
  idx -= DI * XDS;
  if (idx < 2 * DI * DM) {                       // inpT[c][r] = ipw[r][c]
    int r = idx / DM, c = idx % DM;
    inpT[(size_t)c * (2 * DI) + r] = ipw[idx];
    return;
  }
  idx -= 2 * DI * DM;
  if (idx < DM * DI) {                           // outpT[c][r] = opw[r][c]
    int r = idx / DI, c = idx % DI;
    outpT[(size_t)c * DM + r] = opw[idx];
  }
}

// ---------------- GEMM: C[M,NN] = A[M,KK] * BT[KK,NN]   (BT pre-transposed) ------
template <int NN, int KK, int TM, int KT>
__launch_bounds__(256)
__global__ void gemm_nt(const float* __restrict__ A, const float* __restrict__ BT,
                        float* __restrict__ C, int M) {
  constexpr int TN  = 64;
  constexpr int RPT = TM / 16;
  constexpr int SA  = KT + 4;
  constexpr int KQ  = KT / 4;
  __shared__ float As[TM][SA];
  __shared__ float Bs[KT][TN];
  const int t = threadIdx.x;
  const int row0 = blockIdx.y * TM;
  const int col0 = blockIdx.x * TN;
  const int tc = t & 15;
  const int tr = t >> 4;

  float acc[RPT][4];
  #pragma unroll
  for (int i = 0; i < RPT; ++i)
    { acc[i][0]=0.f; acc[i][1]=0.f; acc[i][2]=0.f; acc[i][3]=0.f; }

  for (int k0 = 0; k0 < KK; k0 += KT) {
    #pragma unroll 1
    for (int idx = t; idx < TM * KQ; idx += 256) {
      int r = idx / KQ, kq = idx % KQ;
      *(float4*)&As[r][kq * 4] =
          *(const float4*)&A[(size_t)(row0 + r) * KK + k0 + kq * 4];
    }
    #pragma unroll 1
    for (int idx = t; idx < KT * 16; idx += 256) {
      int kk = idx >> 4, cq = idx & 15;
      int col = col0 + cq * 4;
      float4 v = make_float4(0.f, 0.f, 0.f, 0.f);
      if (col < NN) v = *(const float4*)&BT[(size_t)(k0 + kk) * NN + col];
      *(float4*)&Bs[kk][cq * 4] = v;
    }
    __syncthreads();
    #pragma unroll 4
    for (int kk = 0; kk < KT; ++kk) {
      float4 bv = *(const float4*)&Bs[kk][tc * 4];
      #pragma unroll
      for (int i = 0; i < RPT; ++i) {
        float a = As[tr * RPT + i][kk];
        acc[i][0] += a * bv.x; acc[i][1] += a * bv.y;
        acc[i][2] += a * bv.z; acc[i][3] += a * bv.w;
      }
    }
    __syncthreads();
  }
  int c = col0 + tc * 4;
  if (c < NN) {
    #pragma unroll
    for (int i = 0; i < RPT; ++i) {
      size_t r0 = (size_t)(row0 + tr * RPT + i) * NN + c;
      *(float4*)&C[r0] = make_float4(acc[i][0], acc[i][1], acc[i][2], acc[i][3]);
    }
  }
}

// ---------------- depthwise 3x3 conv + bias + SiLU ----------------
__launch_bounds__(256)
__global__ void conv_silu(const float* __restrict__ xz, const float* __restrict__ cw,
                          const float* __restrict__ cb, float* __restrict__ xc) {
  int idx = blockIdx.x * 256 + threadIdx.x;
  int d = idx % DI;
  int p = (idx / DI) % LSEQ;
  int b = idx / (DI * LSEQ);
  int h = p >> 6, w = p & 63;
  float acc = cb[d];
  #pragma unroll
  for (int kh = 0; kh < 3; ++kh) {
    int hh = h + kh - 1;
    if ((unsigned)hh >= (unsigned)HS) continue;
    #pragma unroll
    for (int kw = 0; kw < 3; ++kw) {
      int ww = w + kw - 1;
      if ((unsigned)ww >= (unsigned)WSZ) continue;
      acc += xz[((size_t)b * LSEQ + (hh << 6) + ww) * (2 * DI) + d] * cw[d * 9 + kh * 3 + kw];
    }
  }
  xc[idx] = acc / (1.f + __expf(-acc));
}

// ---- scan phase 1 (1-wave blocks, d-split x3): local scan + y_loc; hN + sumd ----
// grid: (NCH, KD*3, BATCH); d = (by%3)*64 + t
__launch_bounds__(64)
__global__ void scan_phase1(const float* __restrict__ xc, const float* __restrict__ xdbl,
                            const float* __restrict__ Alog, const float* __restrict__ dtw,
                            const float* __restrict__ dtb,
                            float* __restrict__ hN, float* __restrict__ sumdB,
                            float* __restrict__ ypl) {
  const int t = threadIdx.x;
  const int ch = blockIdx.x, b = blockIdx.z;
  const int k = blockIdx.y / 3;
  const int d = (blockIdx.y % 3) * 64 + t;
  const int bk = b * KD + k;
  __shared__ float4 Bsh[CLEN * 10];         // per pos: B(0..3) C(4..7) dt(8,9)
  #pragma unroll 1
  for (int idx = t; idx < CLEN * 10; idx += 64) {
    int j = idx / 10, q = idx % 10;
    int p = pos_of(k, ch * CLEN + j);
    Bsh[idx] = *(const float4*)&xdbl[(size_t)(b * LSEQ + p) * XDS + k * 40 + q * 4];
  }
  float Al[NS];
  {
    const float4* Ap = (const float4*)&Alog[((size_t)k * DI + d) * NS];
    #pragma unroll
    for (int q = 0; q < 4; ++q) {
      float4 a = Ap[q];
      Al[q*4+0] = a.x; Al[q*4+1] = a.y; Al[q*4+2] = a.z; Al[q*4+3] = a.w;
    }
  }
  const bool geo = geo_check(Al);
  const float An0 = -__expf(Al[0]);
  float w[RK];
  #pragma unroll
  for (int r = 0; r < RK; ++r) w[r] = dtw[((size_t)k * DI + d) * RK + r];
  const float bsv = dtb[k * DI + d];
  __syncthreads();

  float h[NS];
  #pragma unroll
  for (int n = 0; n < NS; ++n) h[n] = 0.f;
  float sumd = 0.f;
  float* yout = ypl + (size_t)bk * LSEQ * DI;
  const int l0 = ch * CLEN;
  if (geo) {
    #pragma unroll 2
    for (int j = 0; j < CLEN; ++j) {
      const int p = pos_of(k, l0 + j);
      const size_t bp = (size_t)b * LSEQ + p;
      float4 t0 = Bsh[j * 10 + 8], t1 = Bsh[j * 10 + 9];
      float dl = softplus_f(dt6(w, bsv, t0, t1));
      float du = dl * xc[bp * DI + d];
      float pw[17];
      pw16(__expf(dl * An0), pw);
      float y = 0.f;
      #pragma unroll
      for (int q = 0; q < 4; ++q) {
        float4 v  = Bsh[j * 10 + q];
        float4 c4 = Bsh[j * 10 + 4 + q];
        h[q*4+0] = pw[q*4+1] * h[q*4+0] + du * v.x; y += h[q*4+0] * c4.x;
        h[q*4+1] = pw[q*4+2] * h[q*4+1] + du * v.y; y += h[q*4+1] * c4.y;
        h[q*4+2] = pw[q*4+3] * h[q*4+2] + du * v.z; y += h[q*4+2] * c4.z;
        h[q*4+3] = pw[q*4+4] * h[q*4+3] + du * v.w; y += h[q*4+3] * c4.w;
      }
      sumd += dl;
      yout[(size_t)p * DI + d] = y;
    }
  } else {
    float An[NS];
    #pragma unroll
    for (int n = 0; n < NS; ++n) An[n] = -__expf(Al[n]);
    #pragma unroll 1
    for (int j = 0; j < CLEN; ++j) {
      const int p = pos_of(k, l0 + j);
      const size_t bp = (size_t)b * LSEQ + p;
      float4 t0 = Bsh[j * 10 + 8], t1 = Bsh[j * 10 + 9];
      float dl = softplus_f(dt6(w, bsv, t0, t1));
      float du = dl * xc[bp * DI + d];
      float y = 0.f;
      #pragma unroll
      for (int q = 0; q < 4; ++q) {
        float4 v  = Bsh[j * 10 + q];
        float4 c4 = Bsh[j * 10 + 4 + q];
        h[q*4+0] = __expf(dl * An[q*4+0]) * h[q*4+0] + du * v.x; y += h[q*4+0] * c4.x;
        h[q*4+1] = __expf(dl * An[q*4+1]) * h[q*4+1] + du * v.y; y += h[q*4+1] * c4.y;
        h[q*4+2] = __expf(dl * An[q*4+2]) * h[q*4+2] + du * v.z; y += h[q*4+2] * c4.z;
        h[q*4+3] = __expf(dl * An[q*4+3]) * h[q*4+3] + du * v.w; y += h[q*4+3] * c4.w;
      }
      sumd += dl;
      yout[(size_t)p * DI + d] = y;
    }
  }
  const size_t o = ((size_t)bk * NCH + ch) * DI + d;
  float4* Hp = (float4*)&hN[o * NS];
  #pragma unroll
  for (int q = 0; q < 4; ++q)
    Hp[q] = make_float4(h[q*4+0], h[q*4+1], h[q*4+2], h[q*4+3]);
  sumdB[o] = sumd;
}

// ---- fused hierarchical combine: one block per (bk,d): 16 n x 16 groups --------
// A: per-group aggregates in regs; B: 16-step LDS scan (lanes g==0);
// C: re-walk using cached w/h values (no hN re-read).
__launch_bounds__(256)
__global__ void combine_all(float* __restrict__ hN, const float* __restrict__ sumdB,
                            const float* __restrict__ Alog) {
  const int t = threadIdx.x;
  const int n = t & 15;
  const int g = t >> 4;
  const int d = blockIdx.x;
  const int k = blockIdx.y, b = blockIdx.z;
  const int bk = b * KD + k;
  const float An = -__expf(Alog[((size_t)k * DI + d) * NS + n]);
  __shared__ float Wl[GCH][NS], Tl[GCH][NS], Hl[GCH][NS];

  float wreg[GLEN], hreg[GLEN];
  float W = 1.f, T = 0.f;
  #pragma unroll
  for (int j = 0; j < GLEN; ++j) {
    const int c = g * GLEN + j;
    const size_t o = ((size_t)bk * NCH + c) * DI + d;
    float wv = __expf(An * sumdB[o]);
    float hv = hN[o * NS + n];
    wreg[j] = wv; hreg[j] = hv;
    T = hv + wv * T;
    W *= wv;
  }
  Wl[g][n] = W; Tl[g][n] = T;
  __syncthreads();
  if (g == 0) {                 // lanes 0..15 scan the 16 group aggregates
    float H = 0.f;
    #pragma unroll
    for (int g2 = 0; g2 < GCH; ++g2) {
      float Wv = Wl[g2][n], Tv = Tl[g2][n];
      Hl[g2][n] = H;
      H = Tv + Wv * H;
    }
  }
  __syncthreads();
  float e = Hl[g][n];
  #pragma unroll
  for (int j = 0; j < GLEN; ++j) {
    const int c = g * GLEN + j;
    const size_t o = ((size_t)bk * NCH + c) * DI + d;
    hN[o * NS + n] = e;
    e = hreg[j] + wreg[j] * e;
  }
}

// ---- scan correction (1-wave blocks, d-split x3): ypl[p] += C.(h0*exp(An*cum)) --
__launch_bounds__(64)
__global__ void scan_corr(const float* __restrict__ xdbl, const float* __restrict__ Alog,
                          const float* __restrict__ dtw, const float* __restrict__ dtb,
                          const float* __restrict__ hin, float* __restrict__ ypl) {
  const int t = threadIdx.x;
  const int ch = blockIdx.x + 1;            // ch=0 has zero entry state
  const int b = blockIdx.z;
  const int k = blockIdx.y / 3;
  const int d = (blockIdx.y % 3) * 64 + t;
  const int bk = b * KD + k;
  __shared__ float4 Bsh[CLEN * 6];          // per pos: C(q4..7) dt(q8,q9)
  #pragma unroll 1
  for (int idx = t; idx < CLEN * 6; idx += 64) {
    int j = idx / 6, q = idx % 6;
    int p = pos_of(k, ch * CLEN + j);
    Bsh[idx] = *(const float4*)&xdbl[(size_t)(b * LSEQ + p) * XDS + k * 40 + (q + 4) * 4];
  }
  float Al[NS];
  {
    const float4* Ap = (const float4*)&Alog[((size_t)k * DI + d) * NS];
    #pragma unroll
    for (int q = 0; q < 4; ++q) {
      float4 a = Ap[q];
      Al[q*4+0] = a.x; Al[q*4+1] = a.y; Al[q*4+2] = a.z; Al[q*4+3] = a.w;
    }
  }
  const bool geo = geo_check(Al);
  const float An0 = -__expf(Al[0]);
  float w[RK];
  #pragma unroll
  for (int r = 0; r < RK; ++r) w[r] = dtw[((size_t)k * DI + d) * RK + r];
  const float bsv = dtb[k * DI + d];

  float g[NS];                              // entry state h0
  {
    const size_t o = ((size_t)bk * NCH + ch) * DI + d;
    const float4* Hp = (const float4*)&hin[o * NS];
    #pragma unroll
    for (int q = 0; q < 4; ++q) {
      float4 v = Hp[q];
      g[q*4+0] = v.x; g[q*4+1] = v.y; g[q*4+2] = v.z; g[q*4+3] = v.w;
    }
  }
  __syncthreads();
  float* yout = ypl + (size_t)bk * LSEQ * DI;
  const int l0 = ch * CLEN;
  float cum = 0.f;
  if (geo) {
    #pragma unroll 2
    for (int j = 0; j < CLEN; ++j) {
      const int p = pos_of(k, l0 + j);
      float4 t0 = Bsh[j * 6 + 4], t1 = Bsh[j * 6 + 5];
      cum += softplus_f(dt6(w, bsv, t0, t1));
      float pw[17];
      pw16(__expf(cum * An0), pw);
      float y = 0.f;
      #pragma unroll
      for (int q = 0; q < 4; ++q) {
        float4 c4 = Bsh[j * 6 + q];
        y += (pw[q*4+1] * g[q*4+0]) * c4.x;
        y += (pw[q*4+2] * g[q*4+1]) * c4.y;
        y += (pw[q*4+3] * g[q*4+2]) * c4.z;
        y += (pw[q*4+4] * g[q*4+3]) * c4.w;
      }
      yout[(size_t)p * DI + d] += y;
    }
  } else {
    float An[NS];
    #pragma unroll
    for (int n = 0; n < NS; ++n) An[n] = -__expf(Al[n]);
    #pragma unroll 1
    for (int j = 0; j < CLEN; ++j) {
      const int p = pos_of(k, l0 + j);
      float4 t0 = Bsh[j * 6 + 4], t1 = Bsh[j * 6 + 5];
      cum += softplus_f(dt6(w, bsv, t0, t1));
      float y = 0.f;
      #pragma unroll
      for (int q = 0; q < 4; ++q) {
        float4 c4 = Bsh[j * 6 + q];
        y += (__expf(An[q*4+0] * cum) * g[q*4+0]) * c4.x;
        y += (__expf(An[q*4+1] * cum) * g[q*4+1]) * c4.y;
        y += (__expf(An[q*4+2] * cum) * g[q*4+2]) * c4.z;
        y += (__expf(An[q*4+3] * cum) * g[q*4+3]) * c4.w;
      }
      yout[(size_t)p * DI + d] += y;
    }
  }
}

// -------- 4-plane merge (Ds term) + LayerNorm + SiLU gate ----------------
__launch_bounds__(192)
__global__ void fuse_ln(const float* __restrict__ ypl, const float* __restrict__ xc,
                        const float* __restrict__ Ds, const float* __restrict__ xz,
                        const float* __restrict__ lnw, const float* __restrict__ lnb,
                        float* __restrict__ ymul) {
  const int row = blockIdx.x;           // b*L + p
  const int b = row >> 12;
  const size_t pd = (size_t)row * DI + threadIdx.x;
  const int d = threadIdx.x;
  constexpr size_t PL = (size_t)LSEQ * DI;
  float u = xc[pd];
  float sDs = Ds[d] + Ds[DI + d] + Ds[2 * DI + d] + Ds[3 * DI + d];
  const size_t base = (size_t)(b * KD) * PL + pd - (size_t)b * PL;
  float y = ypl[base] + ypl[base + PL] + ypl[base + 2 * PL] + ypl[base + 3 * PL] + sDs * u;
  float s1 = y, s2 = y * y;
  #pragma unroll
  for (int off = 32; off; off >>= 1) {
    s1 += __shfl_xor(s1, off);
    s2 += __shfl_xor(s2, off);
  }
  __shared__ float r1[3], r2[3];
  int wid = d >> 6;
  if ((d & 63) == 0) { r1[wid] = s1; r2[wid] = s2; }
  __syncthreads();
  float S1 = r1[0] + r1[1] + r1[2];
  float S2 = r2[0] + r2[1] + r2[2];
  float mu = S1 * (1.f / DI);
  float var = S2 * (1.f / DI) - mu * mu;
  float yn = (y - mu) * rsqrtf(var + 1e-5f) * lnw[d] + lnb[d];
  float zv = xz[(size_t)row * (2 * DI) + DI + d];
  float g = zv / (1.f + __expf(-zv));
  ymul[pd] = yn * g;
}

// ---------------- launcher ----------------
extern "C" void kernel_launch(void* const* d_in, const int* in_sizes, int n_in,
                              void* d_out, int out_size, void* d_ws, size_t ws_size,
                              hipStream_t stream) {
  (void)in_sizes; (void)n_in; (void)out_size; (void)ws_size;
  const float* x          = (const float*)d_in[0];
  const float* in_proj_w  = (const float*)d_in[1];
  const float* conv_w     = (const float*)d_in[2];
  const float* conv_b     = (const float*)d_in[3];
  const float* x_proj_w   = (const float*)d_in[4];
  const float* dt_w       = (const float*)d_in[5];
  const float* dt_b       = (const float*)d_in[6];
  const float* A_logs     = (const float*)d_in[7];
  const float* Ds         = (const float*)d_in[8];
  const float* ln_w       = (const float*)d_in[9];
  const float* ln_b       = (const float*)d_in[10];
  const float* out_proj_w = (const float*)d_in[11];
  float* out = (float*)d_out;
  float* ws  = (float*)d_ws;

  constexpr size_t SZ_XZ    = (size_t)BATCH * LSEQ * 2 * DI;
  constexpr size_t SZ_XC    = (size_t)BATCH * LSEQ * DI;
  constexpr size_t SZ_XD    = (size_t)BATCH * LSEQ * XDS;
  constexpr size_t SZ_HN    = (size_t)BATCH * KD * NCH * DI * NS;   // 25 MB
  constexpr size_t SZ_SUMD  = (size_t)BATCH * KD * NCH * DI;
  constexpr size_t SZ_YPL   = (size_t)BATCH * KD * LSEQ * DI;

  float* xz    = ws;
  float* xc    = xz + SZ_XZ;
  float* xdbl  = xc + SZ_XC;
  float* hN    = xdbl + SZ_XD;
  float* sumd  = hN + SZ_HN;
  float* ypl   = sumd + SZ_SUMD;
  float* WcatT = ypl + SZ_YPL;
  float* inpT  = WcatT + (size_t)DI * XDS;
  float* outpT = inpT + (size_t)DM * 2 * DI;
  float* ymul  = hN;    // hN dead after scan_corr; reuse for LN output

  const int M = BATCH * LSEQ;  // 16384
  const int PREP = DI * XDS + 2 * DI * DM + DM * DI;

  // 0. weight prep (merged)
  prep_weights<<<(PREP + 255) / 256, 256, 0, stream>>>(x_proj_w, in_proj_w, out_proj_w,
                                                       WcatT, inpT, outpT);
  // 1. in_proj
  gemm_nt<2 * DI, DM, 64, 96><<<dim3(6, M / 64), 256, 0, stream>>>(x, inpT, xz, M);
  // 2. depthwise conv + SiLU -> xc
  conv_silu<<<(BATCH * LSEQ * DI) / 256, 256, 0, stream>>>(xz, conv_w, conv_b, xc);
  // 3. x_proj all directions: xdbl[M,160]
  gemm_nt<XDS, DI, 64, 96><<<dim3(3, M / 64), 256, 0, stream>>>(xc, WcatT, xdbl, M);
  // 4. scan phase 1 (1-wave blocks): local scan + y_loc -> planes
  scan_phase1<<<dim3(NCH, KD * 3, BATCH), 64, 0, stream>>>(xc, xdbl, A_logs, dt_w, dt_b,
                                                           hN, sumd, ypl);
  // 5. fused hierarchical combine (hN -> entry states, in place)
  combine_all<<<dim3(DI, KD, BATCH), 256, 0, stream>>>(hN, sumd, A_logs);
  // 6. correction (1-wave blocks): ypl += C . (h0 * exp(An*cumDelta))
  scan_corr<<<dim3(NCH - 1, KD * 3, BATCH), 64, 0, stream>>>(xdbl, A_logs, dt_w, dt_b,
                                                             hN, ypl);
  // 7. merge 4 planes + LN + gate -> ymul (aliases hN)
  fuse_ln<<<M, DI, 0, stream>>>(ypl, xc, Ds, xz, ln_w, ln_b, ymul);
  // 8. out_proj
  gemm_nt<DM, DI, 64, 96><<<dim3(2, M / 64), 256, 0, stream>>>(ymul, outpT, out, M);
}

// Round 17
// 215.264 us; speedup vs baseline: 1.1294x; 1.0151x over previous
//
#include <hip/hip_runtime.h>

// ---------------- problem constants ----------------
constexpr int BATCH = 4;
constexpr int HS    = 64;     // H
constexpr int WSZ   = 64;     // W
constexpr int LSEQ  = 4096;   // L = H*W
constexpr int DM    = 96;     // d_model
constexpr int DI    = 192;    // d_inner
constexpr int NS    = 16;     // d_state
constexpr int RK    = 6;      // dt_rank
constexpr int KD    = 4;      // scan directions
constexpr int NCH   = 128;    // chunks along L
constexpr int CLEN  = 32;     // chunk length
constexpr int XDS   = 160;    // packed xdbl row: 4 * [B(16) C(16) dt(6) pad(2)]
constexpr int GCH   = 16;     // combine groups
constexpr int GLEN  = NCH / GCH;  // 8 chunks per group

// scan index l -> spatial position p (row-major h*64+w), per direction
__device__ __forceinline__ int pos_of(int k, int l) {
  switch (k & 3) {
    case 0: return l;
    case 1: return ((l & 63) << 6) | (l >> 6);
    case 2: return LSEQ - 1 - l;
    default: { int lp = LSEQ - 1 - l; return ((lp & 63) << 6) | (lp >> 6); }
  }
}

// within a chunk (l0 mod 32 == 0), pos_of(k, l0+j) = pos_of(k,l0) + j*step
__device__ __forceinline__ int pos_step(int k) {
  switch (k & 3) {
    case 0: return 1;
    case 1: return 64;
    case 2: return -1;
    default: return -64;
  }
}

__device__ __forceinline__ float softplus_f(float s) {
  return (s > 20.f) ? s : __logf(1.f + __expf(s));
}

// log-depth powers: p[i] = e^i for i=1..16 (depth <= 4, 15 muls)
__device__ __forceinline__ void pw16(float e, float* p) {
  float e2 = e * e, e4 = e2 * e2, e8 = e4 * e4;
  p[1] = e;       p[2] = e2;      p[3] = e2 * e;  p[4] = e4;
  p[5] = e4 * e;  p[6] = e4 * e2; p[7] = p[6] * e; p[8] = e8;
  p[9] = e8 * e;  p[10] = e8 * e2; p[11] = p[10] * e; p[12] = e8 * e4;
  p[13] = p[12] * e; p[14] = p[12] * e2; p[15] = p[14] * e; p[16] = e8 * e8;
}

// geo check on A_logs directly: Alog[n] == Alog[0] + ln(n+1)
__device__ __forceinline__ bool geo_check(const float* Al) {
  const float lntab[16] = {0.f, 0.6931472f, 1.0986123f, 1.3862944f, 1.6094379f,
                           1.7917595f, 1.9459101f, 2.0794415f, 2.1972246f, 2.3025851f,
                           2.3978953f, 2.4849066f, 2.5649494f, 2.6390573f, 2.7080502f,
                           2.7725887f};
  bool g = true;
  #pragma unroll
  for (int n = 0; n < NS; ++n)
    g = g && (fabsf(Al[n] - Al[0] - lntab[n]) <= 2e-3f);
  return g;
}

__device__ __forceinline__ float dt6(const float* w, float bsv, float4 t0, float4 t1) {
  return bsv + w[0]*t0.x + w[1]*t0.y + w[2]*t0.z + w[3]*t0.w + w[4]*t1.x + w[5]*t1.y;
}

// ---------------- merged weight prep: WcatT[192][160], inpT[96][384], outpT[192][96]
__launch_bounds__(256)
__global__ void prep_weights(const float* __restrict__ xw, const float* __restrict__ ipw,
                             const float* __restrict__ opw, float* __restrict__ WcatT,
                             float* __restrict__ inpT, float* __restrict__ outpT) {
  int idx = blockIdx.x * 256 + threadIdx.x;
  if (idx < DI * XDS) {                          // WcatT
    int col = idx / XDS, j = idx % XDS;
    int k = j / 40, jj = j % 40;
    float v = 0.f;
    int src = -1;
    if (jj < 16)      src = k * 38 + 6 + jj;
    else if (jj < 32) src = k * 38 + 22 + (jj - 16);
    else if (jj < 38) src = k * 38 + (jj - 32);
    if (src >= 0) v = xw[(size_t)src * DI + col];
    WcatT[idx] = v;
    return;
  }
  idx -= DI * XDS;
  if (idx < 2 * DI * DM) {                       // inpT[c][r] = ipw[r][c]
    int r = idx / DM, c = idx % DM;
    inpT[(size_t)c * (2 * DI) + r] = ipw[idx];
    return;
  }
  idx -= 2 * DI * DM;
  if (idx < DM * DI) {                           // outpT[c][r] = opw[r][c]
    int r = idx / DI, c = idx % DI;
    outpT[(size_t)c * DM + r] = opw[idx];
  }
}

// ---------------- GEMM: C[M,NN] = A[M,KK] * BT[KK,NN]   (BT pre-transposed) ------
template <int NN, int KK, int TM, int KT>
__launch_bounds__(256)
__global__ void gemm_nt(const float* __restrict__ A, const float* __restrict__ BT,
                        float* __restrict__ C, int M) {
  constexpr int TN  = 64;
  constexpr int RPT = TM / 16;
  constexpr int SA  = KT + 4;
  constexpr int KQ  = KT / 4;
  __shared__ float As[TM][SA];
  __shared__ float Bs[KT][TN];
  const int t = threadIdx.x;
  const int row0 = blockIdx.y * TM;
  const int col0 = blockIdx.x * TN;
  const int tc = t & 15;
  const int tr = t >> 4;

  float acc[RPT][4];
  #pragma unroll
  for (int i = 0; i < RPT; ++i)
    { acc[i][0]=0.f; acc[i][1]=0.f; acc[i][2]=0.f; acc[i][3]=0.f; }

  for (int k0 = 0; k0 < KK; k0 += KT) {
    #pragma unroll 1
    for (int idx = t; idx < TM * KQ; idx += 256) {
      int r = idx / KQ, kq = idx % KQ;
      *(float4*)&As[r][kq * 4] =
          *(const float4*)&A[(size_t)(row0 + r) * KK + k0 + kq * 4];
    }
    #pragma unroll 1
    for (int idx = t; idx < KT * 16; idx += 256) {
      int kk = idx >> 4, cq = idx & 15;
      int col = col0 + cq * 4;
      float4 v = make_float4(0.f, 0.f, 0.f, 0.f);
      if (col < NN) v = *(const float4*)&BT[(size_t)(k0 + kk) * NN + col];
      *(float4*)&Bs[kk][cq * 4] = v;
    }
    __syncthreads();
    #pragma unroll 4
    for (int kk = 0; kk < KT; ++kk) {
      float4 bv = *(const float4*)&Bs[kk][tc * 4];
      #pragma unroll
      for (int i = 0; i < RPT; ++i) {
        float a = As[tr * RPT + i][kk];
        acc[i][0] += a * bv.x; acc[i][1] += a * bv.y;
        acc[i][2] += a * bv.z; acc[i][3] += a * bv.w;
      }
    }
    __syncthreads();
  }
  int c = col0 + tc * 4;
  if (c < NN) {
    #pragma unroll
    for (int i = 0; i < RPT; ++i) {
      size_t r0 = (size_t)(row0 + tr * RPT + i) * NN + c;
      *(float4*)&C[r0] = make_float4(acc[i][0], acc[i][1], acc[i][2], acc[i][3]);
    }
  }
}

// ---------------- depthwise 3x3 conv + bias + SiLU ----------------
__launch_bounds__(256)
__global__ void conv_silu(const float* __restrict__ xz, const float* __restrict__ cw,
                          const float* __restrict__ cb, float* __restrict__ xc) {
  int idx = blockIdx.x * 256 + threadIdx.x;
  int d = idx % DI;
  int p = (idx / DI) % LSEQ;
  int b = idx / (DI * LSEQ);
  int h = p >> 6, w = p & 63;
  float acc = cb[d];
  #pragma unroll
  for (int kh = 0; kh < 3; ++kh) {
    int hh = h + kh - 1;
    if ((unsigned)hh >= (unsigned)HS) continue;
    #pragma unroll
    for (int kw = 0; kw < 3; ++kw) {
      int ww = w + kw - 1;
      if ((unsigned)ww >= (unsigned)WSZ) continue;
      acc += xz[((size_t)b * LSEQ + (hh << 6) + ww) * (2 * DI) + d] * cw[d * 9 + kh * 3 + kw];
    }
  }
  xc[idx] = acc / (1.f + __expf(-acc));
}

// ---- scan phase 1: local scan + y_loc (pointer-walk); hN + sumd -----------------
__launch_bounds__(192)
__global__ void scan_phase1(const float* __restrict__ xc, const float* __restrict__ xdbl,
                            const float* __restrict__ Alog, const float* __restrict__ dtw,
                            const float* __restrict__ dtb,
                            float* __restrict__ hN, float* __restrict__ sumdB,
                            float* __restrict__ ypl) {
  const int d = threadIdx.x;
  const int ch = blockIdx.x, k = blockIdx.y, b = blockIdx.z;
  const int bk = b * KD + k;
  __shared__ float4 Bsh[CLEN * 10];         // per pos: B(0..3) C(4..7) dt(8,9)
  #pragma unroll 1
  for (int idx = d; idx < CLEN * 10; idx += 192) {
    int j = idx / 10, q = idx % 10;
    int p = pos_of(k, ch * CLEN + j);
    Bsh[idx] = *(const float4*)&xdbl[(size_t)(b * LSEQ + p) * XDS + k * 40 + q * 4];
  }
  float Al[NS];
  {
    const float4* Ap = (const float4*)&Alog[((size_t)k * DI + d) * NS];
    #pragma unroll
    for (int q = 0; q < 4; ++q) {
      float4 a = Ap[q];
      Al[q*4+0] = a.x; Al[q*4+1] = a.y; Al[q*4+2] = a.z; Al[q*4+3] = a.w;
    }
  }
  const bool geo = geo_check(Al);
  const float An0 = -__expf(Al[0]);
  float w[RK];
  #pragma unroll
  for (int r = 0; r < RK; ++r) w[r] = dtw[((size_t)k * DI + d) * RK + r];
  const float bsv = dtb[k * DI + d];
  __syncthreads();

  float h[NS];
  #pragma unroll
  for (int n = 0; n < NS; ++n) h[n] = 0.f;
  float sumd = 0.f;
  const int l0 = ch * CLEN;
  const int p0 = pos_of(k, l0);
  const long pstride = (long)pos_step(k) * DI;
  const float* xcp = xc + ((size_t)b * LSEQ + p0) * DI + d;
  float* youtp = ypl + ((size_t)bk * LSEQ + p0) * DI + d;
  if (geo) {
    #pragma unroll 2
    for (int j = 0; j < CLEN; ++j) {
      float4 t0 = Bsh[j * 10 + 8], t1 = Bsh[j * 10 + 9];
      float dl = softplus_f(dt6(w, bsv, t0, t1));
      float du = dl * (*xcp);
      float pw[17];
      pw16(__expf(dl * An0), pw);
      float y = 0.f;
      #pragma unroll
      for (int q = 0; q < 4; ++q) {
        float4 v  = Bsh[j * 10 + q];
        float4 c4 = Bsh[j * 10 + 4 + q];
        h[q*4+0] = pw[q*4+1] * h[q*4+0] + du * v.x; y += h[q*4+0] * c4.x;
        h[q*4+1] = pw[q*4+2] * h[q*4+1] + du * v.y; y += h[q*4+1] * c4.y;
        h[q*4+2] = pw[q*4+3] * h[q*4+2] + du * v.z; y += h[q*4+2] * c4.z;
        h[q*4+3] = pw[q*4+4] * h[q*4+3] + du * v.w; y += h[q*4+3] * c4.w;
      }
      sumd += dl;
      *youtp = y;
      xcp += pstride; youtp += pstride;
    }
  } else {
    float An[NS];
    #pragma unroll
    for (int n = 0; n < NS; ++n) An[n] = -__expf(Al[n]);
    #pragma unroll 1
    for (int j = 0; j < CLEN; ++j) {
      float4 t0 = Bsh[j * 10 + 8], t1 = Bsh[j * 10 + 9];
      float dl = softplus_f(dt6(w, bsv, t0, t1));
      float du = dl * (*xcp);
      float y = 0.f;
      #pragma unroll
      for (int q = 0; q < 4; ++q) {
        float4 v  = Bsh[j * 10 + q];
        float4 c4 = Bsh[j * 10 + 4 + q];
        h[q*4+0] = __expf(dl * An[q*4+0]) * h[q*4+0] + du * v.x; y += h[q*4+0] * c4.x;
        h[q*4+1] = __expf(dl * An[q*4+1]) * h[q*4+1] + du * v.y; y += h[q*4+1] * c4.y;
        h[q*4+2] = __expf(dl * An[q*4+2]) * h[q*4+2] + du * v.z; y += h[q*4+2] * c4.z;
        h[q*4+3] = __expf(dl * An[q*4+3]) * h[q*4+3] + du * v.w; y += h[q*4+3] * c4.w;
      }
      sumd += dl;
      *youtp = y;
      xcp += pstride; youtp += pstride;
    }
  }
  const size_t o = ((size_t)bk * NCH + ch) * DI + d;
  float4* Hp = (float4*)&hN[o * NS];
  #pragma unroll
  for (int q = 0; q < 4; ++q)
    Hp[q] = make_float4(h[q*4+0], h[q*4+1], h[q*4+2], h[q*4+3]);
  sumdB[o] = sumd;
}

// ---- fused hierarchical combine: one block per (bk,d): 16 n x 16 groups --------
__launch_bounds__(256)
__global__ void combine_all(float* __restrict__ hN, const float* __restrict__ sumdB,
                            const float* __restrict__ Alog) {
  const int t = threadIdx.x;
  const int n = t & 15;
  const int g = t >> 4;
  const int d = blockIdx.x;
  const int k = blockIdx.y, b = blockIdx.z;
  const int bk = b * KD + k;
  const float An = -__expf(Alog[((size_t)k * DI + d) * NS + n]);
  __shared__ float Wl[GCH][NS], Tl[GCH][NS], Hl[GCH][NS];

  float wreg[GLEN], hreg[GLEN];
  float W = 1.f, T = 0.f;
  #pragma unroll
  for (int j = 0; j < GLEN; ++j) {
    const int c = g * GLEN + j;
    const size_t o = ((size_t)bk * NCH + c) * DI + d;
    float wv = __expf(An * sumdB[o]);
    float hv = hN[o * NS + n];
    wreg[j] = wv; hreg[j] = hv;
    T = hv + wv * T;
    W *= wv;
  }
  Wl[g][n] = W; Tl[g][n] = T;
  __syncthreads();
  if (g == 0) {
    float H = 0.f;
    #pragma unroll
    for (int g2 = 0; g2 < GCH; ++g2) {
      float Wv = Wl[g2][n], Tv = Tl[g2][n];
      Hl[g2][n] = H;
      H = Tv + Wv * H;
    }
  }
  __syncthreads();
  float e = Hl[g][n];
  #pragma unroll
  for (int j = 0; j < GLEN; ++j) {
    const int c = g * GLEN + j;
    const size_t o = ((size_t)bk * NCH + c) * DI + d;
    hN[o * NS + n] = e;
    e = hreg[j] + wreg[j] * e;
  }
}

// ---- scan correction (pointer-walk): ypl[p] += C . (h0 * exp(An*cum)) ----------
__launch_bounds__(192)
__global__ void scan_corr(const float* __restrict__ xdbl, const float* __restrict__ Alog,
                          const float* __restrict__ dtw, const float* __restrict__ dtb,
                          const float* __restrict__ hin, float* __restrict__ ypl) {
  const int d = threadIdx.x;
  const int ch = blockIdx.x + 1;            // ch=0 has zero entry state
  const int k = blockIdx.y, b = blockIdx.z;
  const int bk = b * KD + k;
  __shared__ float4 Bsh[CLEN * 6];          // per pos: C(q4..7) dt(q8,q9)
  {
    int idx = d;                            // CLEN*6 == 192
    int j = idx / 6, q = idx % 6;
    int p = pos_of(k, ch * CLEN + j);
    Bsh[idx] = *(const float4*)&xdbl[(size_t)(b * LSEQ + p) * XDS + k * 40 + (q + 4) * 4];
  }
  float Al[NS];
  {
    const float4* Ap = (const float4*)&Alog[((size_t)k * DI + d) * NS];
    #pragma unroll
    for (int q = 0; q < 4; ++q) {
      float4 a = Ap[q];
      Al[q*4+0] = a.x; Al[q*4+1] = a.y; Al[q*4+2] = a.z; Al[q*4+3] = a.w;
    }
  }
  const bool geo = geo_check(Al);
  const float An0 = -__expf(Al[0]);
  float w[RK];
  #pragma unroll
  for (int r = 0; r < RK; ++r) w[r] = dtw[((size_t)k * DI + d) * RK + r];
  const float bsv = dtb[k * DI + d];

  float g[NS];                              // entry state h0
  {
    const size_t o = ((size_t)bk * NCH + ch) * DI + d;
    const float4* Hp = (const float4*)&hin[o * NS];
    #pragma unroll
    for (int q = 0; q < 4; ++q) {
      float4 v = Hp[q];
      g[q*4+0] = v.x; g[q*4+1] = v.y; g[q*4+2] = v.z; g[q*4+3] = v.w;
    }
  }
  __syncthreads();
  const int l0 = ch * CLEN;
  const int p0 = pos_of(k, l0);
  const long pstride = (long)pos_step(k) * DI;
  float* youtp = ypl + ((size_t)bk * LSEQ + p0) * DI + d;
  float cum = 0.f;
  if (geo) {
    #pragma unroll 2
    for (int j = 0; j < CLEN; ++j) {
      float4 t0 = Bsh[j * 6 + 4], t1 = Bsh[j * 6 + 5];
      cum += softplus_f(dt6(w, bsv, t0, t1));
      float pw[17];
      pw16(__expf(cum * An0), pw);
      float y = 0.f;
      #pragma unroll
      for (int q = 0; q < 4; ++q) {
        float4 c4 = Bsh[j * 6 + q];
        y += (pw[q*4+1] * g[q*4+0]) * c4.x;
        y += (pw[q*4+2] * g[q*4+1]) * c4.y;
        y += (pw[q*4+3] * g[q*4+2]) * c4.z;
        y += (pw[q*4+4] * g[q*4+3]) * c4.w;
      }
      *youtp += y;
      youtp += pstride;
    }
  } else {
    float An[NS];
    #pragma unroll
    for (int n = 0; n < NS; ++n) An[n] = -__expf(Al[n]);
    #pragma unroll 1
    for (int j = 0; j < CLEN; ++j) {
      float4 t0 = Bsh[j * 6 + 4], t1 = Bsh[j * 6 + 5];
      cum += softplus_f(dt6(w, bsv, t0, t1));
      float y = 0.f;
      #pragma unroll
      for (int q = 0; q < 4; ++q) {
        float4 c4 = Bsh[j * 6 + q];
        y += (__expf(An[q*4+0] * cum) * g[q*4+0]) * c4.x;
        y += (__expf(An[q*4+1] * cum) * g[q*4+1]) * c4.y;
        y += (__expf(An[q*4+2] * cum) * g[q*4+2]) * c4.z;
        y += (__expf(An[q*4+3] * cum) * g[q*4+3]) * c4.w;
      }
      *youtp += y;
      youtp += pstride;
    }
  }
}

// -------- 4-plane merge (Ds term) + LayerNorm + SiLU gate ----------------
__launch_bounds__(192)
__global__ void fuse_ln(const float* __restrict__ ypl, const float* __restrict__ xc,
                        const float* __restrict__ Ds, const float* __restrict__ xz,
                        const float* __restrict__ lnw, const float* __restrict__ lnb,
                        float* __restrict__ ymul) {
  const int row = blockIdx.x;           // b*L + p
  const int b = row >> 12;
  const size_t pd = (size_t)row * DI + threadIdx.x;
  const int d = threadIdx.x;
  constexpr size_t PL = (size_t)LSEQ * DI;
  float u = xc[pd];
  float sDs = Ds[d] + Ds[DI + d] + Ds[2 * DI + d] + Ds[3 * DI + d];
  const size_t base = (size_t)(b * KD) * PL + pd - (size_t)b * PL;
  float y = ypl[base] + ypl[base + PL] + ypl[base + 2 * PL] + ypl[base + 3 * PL] + sDs * u;
  float s1 = y, s2 = y * y;
  #pragma unroll
  for (int off = 32; off; off >>= 1) {
    s1 += __shfl_xor(s1, off);
    s2 += __shfl_xor(s2, off);
  }
  __shared__ float r1[3], r2[3];
  int wid = d >> 6;
  if ((d & 63) == 0) { r1[wid] = s1; r2[wid] = s2; }
  __syncthreads();
  float S1 = r1[0] + r1[1] + r1[2];
  float S2 = r2[0] + r2[1] + r2[2];
  float mu = S1 * (1.f / DI);
  float var = S2 * (1.f / DI) - mu * mu;
  float yn = (y - mu) * rsqrtf(var + 1e-5f) * lnw[d] + lnb[d];
  float zv = xz[(size_t)row * (2 * DI) + DI + d];
  float g = zv / (1.f + __expf(-zv));
  ymul[pd] = yn * g;
}

// ---------------- launcher ----------------
extern "C" void kernel_launch(void* const* d_in, const int* in_sizes, int n_in,
                              void* d_out, int out_size, void* d_ws, size_t ws_size,
                              hipStream_t stream) {
  (void)in_sizes; (void)n_in; (void)out_size; (void)ws_size;
  const float* x          = (const float*)d_in[0];
  const float* in_proj_w  = (const float*)d_in[1];
  const float* conv_w     = (const float*)d_in[2];
  const float* conv_b     = (const float*)d_in[3];
  const float* x_proj_w   = (const float*)d_in[4];
  const float* dt_w       = (const float*)d_in[5];
  const float* dt_b       = (const float*)d_in[6];
  const float* A_logs     = (const float*)d_in[7];
  const float* Ds         = (const float*)d_in[8];
  const float* ln_w       = (const float*)d_in[9];
  const float* ln_b       = (const float*)d_in[10];
  const float* out_proj_w = (const float*)d_in[11];
  float* out = (float*)d_out;
  float* ws  = (float*)d_ws;

  constexpr size_t SZ_XZ    = (size_t)BATCH * LSEQ * 2 * DI;
  constexpr size_t SZ_XC    = (size_t)BATCH * LSEQ * DI;
  constexpr size_t SZ_XD    = (size_t)BATCH * LSEQ * XDS;
  constexpr size_t SZ_HN    = (size_t)BATCH * KD * NCH * DI * NS;   // 25 MB
  constexpr size_t SZ_SUMD  = (size_t)BATCH * KD * NCH * DI;
  constexpr size_t SZ_YPL   = (size_t)BATCH * KD * LSEQ * DI;

  float* xz    = ws;
  float* xc    = xz + SZ_XZ;
  float* xdbl  = xc + SZ_XC;
  float* hN    = xdbl + SZ_XD;
  float* sumd  = hN + SZ_HN;
  float* ypl   = sumd + SZ_SUMD;
  float* WcatT = ypl + SZ_YPL;
  float* inpT  = WcatT + (size_t)DI * XDS;
  float* outpT = inpT + (size_t)DM * 2 * DI;
  float* ymul  = hN;    // hN dead after scan_corr; reuse for LN output

  const int M = BATCH * LSEQ;  // 16384
  const int PREP = DI * XDS + 2 * DI * DM + DM * DI;

  // 0. weight prep (merged)
  prep_weights<<<(PREP + 255) / 256, 256, 0, stream>>>(x_proj_w, in_proj_w, out_proj_w,
                                                       WcatT, inpT, outpT);
  // 1. in_proj
  gemm_nt<2 * DI, DM, 64, 96><<<dim3(6, M / 64), 256, 0, stream>>>(x, inpT, xz, M);
  // 2. depthwise conv + SiLU -> xc
  conv_silu<<<(BATCH * LSEQ * DI) / 256, 256, 0, stream>>>(xz, conv_w, conv_b, xc);
  // 3. x_proj all directions: xdbl[M,160]
  gemm_nt<XDS, DI, 64, 96><<<dim3(3, M / 64), 256, 0, stream>>>(xc, WcatT, xdbl, M);
  // 4. scan phase 1: local scan + y_loc -> planes (pointer-walk)
  scan_phase1<<<dim3(NCH, KD, BATCH), 192, 0, stream>>>(xc, xdbl, A_logs, dt_w, dt_b,
                                                        hN, sumd, ypl);
  // 5. fused hierarchical combine (hN -> entry states, in place)
  combine_all<<<dim3(DI, KD, BATCH), 256, 0, stream>>>(hN, sumd, A_logs);
  // 6. correction: ypl += C . (h0 * exp(An*cumDelta))  (pointer-walk)
  scan_corr<<<dim3(NCH - 1, KD, BATCH), 192, 0, stream>>>(xdbl, A_logs, dt_w, dt_b,
                                                          hN, ypl);
  // 7. merge 4 planes + LN + gate -> ymul (aliases hN)
  fuse_ln<<<M, DI, 0, stream>>>(ypl, xc, Ds, xz, ln_w, ln_b, ymul);
  // 8. out_proj
  gemm_nt<DM, DI, 64, 96><<<dim3(2, M / 64), 256, 0, stream>>>(ymul, outpT, out, M);
}

// Round 18
// 200.821 us; speedup vs baseline: 1.2107x; 1.0719x over previous
//
#include <hip/hip_runtime.h>

// ---------------- problem constants ----------------
constexpr int BATCH = 4;
constexpr int HS    = 64;     // H
constexpr int WSZ   = 64;     // W
constexpr int LSEQ  = 4096;   // L = H*W
constexpr int DM    = 96;     // d_model
constexpr int DI    = 192;    // d_inner
constexpr int NS    = 16;     // d_state
constexpr int RK    = 6;      // dt_rank
constexpr int KD    = 4;      // scan directions
constexpr int NCH   = 128;    // chunks along L
constexpr int CLEN  = 32;     // chunk length
constexpr int XDS   = 160;    // packed xdbl row: 4 * [B(16) C(16) dt(6) pad(2)]
constexpr int GCH   = 16;     // combine groups
constexpr int GLEN  = NCH / GCH;  // 8 chunks per group

typedef float v2f __attribute__((ext_vector_type(2)));

__device__ __forceinline__ v2f mkv2(float a, float b) { v2f r; r.x = a; r.y = b; return r; }

// packed fp32: D = S0*S1 + S2   (pure-register asm; no memory hazards)
__device__ __forceinline__ v2f pk_fma(v2f a, v2f b, v2f c) {
  v2f d;
  asm("v_pk_fma_f32 %0, %1, %2, %3" : "=v"(d) : "v"(a), "v"(b), "v"(c));
  return d;
}
__device__ __forceinline__ v2f pk_mul(v2f a, v2f b) {
  v2f d;
  asm("v_pk_mul_f32 %0, %1, %2" : "=v"(d) : "v"(a), "v"(b));
  return d;
}

// scan index l -> spatial position p (row-major h*64+w), per direction
__device__ __forceinline__ int pos_of(int k, int l) {
  switch (k & 3) {
    case 0: return l;
    case 1: return ((l & 63) << 6) | (l >> 6);
    case 2: return LSEQ - 1 - l;
    default: { int lp = LSEQ - 1 - l; return ((lp & 63) << 6) | (lp >> 6); }
  }
}

// within a chunk (l0 mod 32 == 0), pos_of(k, l0+j) = pos_of(k,l0) + j*step
__device__ __forceinline__ int pos_step(int k) {
  switch (k & 3) {
    case 0: return 1;
    case 1: return 64;
    case 2: return -1;
    default: return -64;
  }
}

__device__ __forceinline__ float softplus_f(float s) {
  return (s > 20.f) ? s : __logf(1.f + __expf(s));
}

// geo check on A_logs directly: Alog[n] == Alog[0] + ln(n+1)
__device__ __forceinline__ bool geo_check(const float* Al) {
  const float lntab[16] = {0.f, 0.6931472f, 1.0986123f, 1.3862944f, 1.6094379f,
                           1.7917595f, 1.9459101f, 2.0794415f, 2.1972246f, 2.3025851f,
                           2.3978953f, 2.4849066f, 2.5649494f, 2.6390573f, 2.7080502f,
                           2.7725887f};
  bool g = true;
  #pragma unroll
  for (int n = 0; n < NS; ++n)
    g = g && (fabsf(Al[n] - Al[0] - lntab[n]) <= 2e-3f);
  return g;
}

// packed dt6: s = bsv + w.t   (w2[3] packed weights)
__device__ __forceinline__ float dt6p(const v2f* w2, float bsv, float4 t0, float4 t1) {
  v2f acc = pk_mul(w2[0], mkv2(t0.x, t0.y));
  acc = pk_fma(w2[1], mkv2(t0.z, t0.w), acc);
  acc = pk_fma(w2[2], mkv2(t1.x, t1.y), acc);
  return bsv + acc.x + acc.y;
}

// packed powers: pw2[q] = {e^(2q+1), e^(2q+2)}, q=0..7
__device__ __forceinline__ void pw8p(float e, v2f* pw2) {
  float e2 = e * e;
  v2f ee2 = mkv2(e2, e2);
  pw2[0] = mkv2(e, e2);
  #pragma unroll
  for (int q = 1; q < 8; ++q) pw2[q] = pk_mul(pw2[q - 1], ee2);
}

__device__ __forceinline__ float dt6(const float* w, float bsv, float4 t0, float4 t1) {
  return bsv + w[0]*t0.x + w[1]*t0.y + w[2]*t0.z + w[3]*t0.w + w[4]*t1.x + w[5]*t1.y;
}

// ---------------- merged weight prep: WcatT[192][160], inpT[96][384], outpT[192][96]
__launch_bounds__(256)
__global__ void prep_weights(const float* __restrict__ xw, const float* __restrict__ ipw,
                             const float* __restrict__ opw, float* __restrict__ WcatT,
                             float* __restrict__ inpT, float* __restrict__ outpT) {
  int idx = blockIdx.x * 256 + threadIdx.x;
  if (idx < DI * XDS) {                          // WcatT
    int col = idx / XDS, j = idx % XDS;
    int k = j / 40, jj = j % 40;
    float v = 0.f;
    int src = -1;
    if (jj < 16)      src = k * 38 + 6 + jj;
    else if (jj < 32) src = k * 38 + 22 + (jj - 16);
    else if (jj < 38) src = k * 38 + (jj - 32);
    if (src >= 0) v = xw[(size_t)src * DI + col];
    WcatT[idx] = v;
    return;
  }
  idx -= DI * XDS;
  if (idx < 2 * DI * DM) {                       // inpT[c][r] = ipw[r][c]
    int r = idx / DM, c = idx % DM;
    inpT[(size_t)c * (2 * DI) + r] = ipw[idx];
    return;
  }
  idx -= 2 * DI * DM;
  if (idx < DM * DI) {                           // outpT[c][r] = opw[r][c]
    int r = idx / DI, c = idx % DI;
    outpT[(size_t)c * DM + r] = opw[idx];
  }
}

// ---------------- GEMM: C[M,NN] = A[M,KK] * BT[KK,NN]   (BT pre-transposed) ------
template <int NN, int KK, int TM, int KT>
__launch_bounds__(256)
__global__ void gemm_nt(const float* __restrict__ A, const float* __restrict__ BT,
                        float* __restrict__ C, int M) {
  constexpr int TN  = 64;
  constexpr int RPT = TM / 16;
  constexpr int SA  = KT + 4;
  constexpr int KQ  = KT / 4;
  __shared__ float As[TM][SA];
  __shared__ float Bs[KT][TN];
  const int t = threadIdx.x;
  const int row0 = blockIdx.y * TM;
  const int col0 = blockIdx.x * TN;
  const int tc = t & 15;
  const int tr = t >> 4;

  float acc[RPT][4];
  #pragma unroll
  for (int i = 0; i < RPT; ++i)
    { acc[i][0]=0.f; acc[i][1]=0.f; acc[i][2]=0.f; acc[i][3]=0.f; }

  for (int k0 = 0; k0 < KK; k0 += KT) {
    #pragma unroll 1
    for (int idx = t; idx < TM * KQ; idx += 256) {
      int r = idx / KQ, kq = idx % KQ;
      *(float4*)&As[r][kq * 4] =
          *(const float4*)&A[(size_t)(row0 + r) * KK + k0 + kq * 4];
    }
    #pragma unroll 1
    for (int idx = t; idx < KT * 16; idx += 256) {
      int kk = idx >> 4, cq = idx & 15;
      int col = col0 + cq * 4;
      float4 v = make_float4(0.f, 0.f, 0.f, 0.f);
      if (col < NN) v = *(const float4*)&BT[(size_t)(k0 + kk) * NN + col];
      *(float4*)&Bs[kk][cq * 4] = v;
    }
    __syncthreads();
    #pragma unroll 4
    for (int kk = 0; kk < KT; ++kk) {
      float4 bv = *(const float4*)&Bs[kk][tc * 4];
      #pragma unroll
      for (int i = 0; i < RPT; ++i) {
        float a = As[tr * RPT + i][kk];
        acc[i][0] += a * bv.x; acc[i][1] += a * bv.y;
        acc[i][2] += a * bv.z; acc[i][3] += a * bv.w;
      }
    }
    __syncthreads();
  }
  int c = col0 + tc * 4;
  if (c < NN) {
    #pragma unroll
    for (int i = 0; i < RPT; ++i) {
      size_t r0 = (size_t)(row0 + tr * RPT + i) * NN + c;
      *(float4*)&C[r0] = make_float4(acc[i][0], acc[i][1], acc[i][2], acc[i][3]);
    }
  }
}

// ---------------- depthwise 3x3 conv + bias + SiLU ----------------
__launch_bounds__(256)
__global__ void conv_silu(const float* __restrict__ xz, const float* __restrict__ cw,
                          const float* __restrict__ cb, float* __restrict__ xc) {
  int idx = blockIdx.x * 256 + threadIdx.x;
  int d = idx % DI;
  int p = (idx / DI) % LSEQ;
  int b = idx / (DI * LSEQ);
  int h = p >> 6, w = p & 63;
  float acc = cb[d];
  #pragma unroll
  for (int kh = 0; kh < 3; ++kh) {
    int hh = h + kh - 1;
    if ((unsigned)hh >= (unsigned)HS) continue;
    #pragma unroll
    for (int kw = 0; kw < 3; ++kw) {
      int ww = w + kw - 1;
      if ((unsigned)ww >= (unsigned)WSZ) continue;
      acc += xz[((size_t)b * LSEQ + (hh << 6) + ww) * (2 * DI) + d] * cw[d * 9 + kh * 3 + kw];
    }
  }
  xc[idx] = acc / (1.f + __expf(-acc));
}

// ---- scan phase 1: local scan + y_loc (packed fp32); hN + sumd ------------------
__launch_bounds__(192)
__global__ void scan_phase1(const float* __restrict__ xc, const float* __restrict__ xdbl,
                            const float* __restrict__ Alog, const float* __restrict__ dtw,
                            const float* __restrict__ dtb,
                            float* __restrict__ hN, float* __restrict__ sumdB,
                            float* __restrict__ ypl) {
  const int d = threadIdx.x;
  const int ch = blockIdx.x, k = blockIdx.y, b = blockIdx.z;
  const int bk = b * KD + k;
  __shared__ float4 Bsh[CLEN * 10];         // per pos: B(0..3) C(4..7) dt(8,9)
  #pragma unroll 1
  for (int idx = d; idx < CLEN * 10; idx += 192) {
    int j = idx / 10, q = idx % 10;
    int p = pos_of(k, ch * CLEN + j);
    Bsh[idx] = *(const float4*)&xdbl[(size_t)(b * LSEQ + p) * XDS + k * 40 + q * 4];
  }
  float Al[NS];
  {
    const float4* Ap = (const float4*)&Alog[((size_t)k * DI + d) * NS];
    #pragma unroll
    for (int q = 0; q < 4; ++q) {
      float4 a = Ap[q];
      Al[q*4+0] = a.x; Al[q*4+1] = a.y; Al[q*4+2] = a.z; Al[q*4+3] = a.w;
    }
  }
  const bool geo = geo_check(Al);
  const float An0 = -__expf(Al[0]);
  float w[RK];
  #pragma unroll
  for (int r = 0; r < RK; ++r) w[r] = dtw[((size_t)k * DI + d) * RK + r];
  const float bsv = dtb[k * DI + d];
  v2f w2[3];
  w2[0] = mkv2(w[0], w[1]); w2[1] = mkv2(w[2], w[3]); w2[2] = mkv2(w[4], w[5]);
  __syncthreads();

  float sumd = 0.f;
  const int l0 = ch * CLEN;
  const int p0 = pos_of(k, l0);
  const long pstride = (long)pos_step(k) * DI;
  const float* xcp = xc + ((size_t)b * LSEQ + p0) * DI + d;
  float* youtp = ypl + ((size_t)bk * LSEQ + p0) * DI + d;
  v2f h2[8];
  #pragma unroll
  for (int q = 0; q < 8; ++q) h2[q] = mkv2(0.f, 0.f);
  if (geo) {
    #pragma unroll 2
    for (int j = 0; j < CLEN; ++j) {
      float4 t0 = Bsh[j * 10 + 8], t1 = Bsh[j * 10 + 9];
      float dl = softplus_f(dt6p(w2, bsv, t0, t1));
      float du = dl * (*xcp);
      v2f du2 = mkv2(du, du);
      v2f pw2[8];
      pw8p(__expf(dl * An0), pw2);
      v2f y2 = mkv2(0.f, 0.f);
      #pragma unroll
      for (int q = 0; q < 4; ++q) {
        float4 v  = Bsh[j * 10 + q];
        float4 c4 = Bsh[j * 10 + 4 + q];
        h2[2*q]   = pk_fma(pw2[2*q],   h2[2*q],   pk_mul(du2, mkv2(v.x, v.y)));
        y2 = pk_fma(h2[2*q],   mkv2(c4.x, c4.y), y2);
        h2[2*q+1] = pk_fma(pw2[2*q+1], h2[2*q+1], pk_mul(du2, mkv2(v.z, v.w)));
        y2 = pk_fma(h2[2*q+1], mkv2(c4.z, c4.w), y2);
      }
      sumd += dl;
      *youtp = y2.x + y2.y;
      xcp += pstride; youtp += pstride;
    }
  } else {
    float An[NS];
    #pragma unroll
    for (int n = 0; n < NS; ++n) An[n] = -__expf(Al[n]);
    float h[NS];
    #pragma unroll
    for (int n = 0; n < NS; ++n) h[n] = 0.f;
    #pragma unroll 1
    for (int j = 0; j < CLEN; ++j) {
      float4 t0 = Bsh[j * 10 + 8], t1 = Bsh[j * 10 + 9];
      float dl = softplus_f(dt6(w, bsv, t0, t1));
      float du = dl * (*xcp);
      float y = 0.f;
      #pragma unroll
      for (int q = 0; q < 4; ++q) {
        float4 v  = Bsh[j * 10 + q];
        float4 c4 = Bsh[j * 10 + 4 + q];
        h[q*4+0] = __expf(dl * An[q*4+0]) * h[q*4+0] + du * v.x; y += h[q*4+0] * c4.x;
        h[q*4+1] = __expf(dl * An[q*4+1]) * h[q*4+1] + du * v.y; y += h[q*4+1] * c4.y;
        h[q*4+2] = __expf(dl * An[q*4+2]) * h[q*4+2] + du * v.z; y += h[q*4+2] * c4.z;
        h[q*4+3] = __expf(dl * An[q*4+3]) * h[q*4+3] + du * v.w; y += h[q*4+3] * c4.w;
      }
      sumd += dl;
      *youtp = y;
      xcp += pstride; youtp += pstride;
    }
    #pragma unroll
    for (int q = 0; q < 8; ++q) h2[q] = mkv2(h[2*q], h[2*q+1]);
  }
  const size_t o = ((size_t)bk * NCH + ch) * DI + d;
  float4* Hp = (float4*)&hN[o * NS];
  #pragma unroll
  for (int q = 0; q < 4; ++q)
    Hp[q] = make_float4(h2[2*q].x, h2[2*q].y, h2[2*q+1].x, h2[2*q+1].y);
  sumdB[o] = sumd;
}

// ---- fused hierarchical combine: one block per (bk,d): 16 n x 16 groups --------
__launch_bounds__(256)
__global__ void combine_all(float* __restrict__ hN, const float* __restrict__ sumdB,
                            const float* __restrict__ Alog) {
  const int t = threadIdx.x;
  const int n = t & 15;
  const int g = t >> 4;
  const int d = blockIdx.x;
  const int k = blockIdx.y, b = blockIdx.z;
  const int bk = b * KD + k;
  const float An = -__expf(Alog[((size_t)k * DI + d) * NS + n]);
  __shared__ float Wl[GCH][NS], Tl[GCH][NS], Hl[GCH][NS];

  float wreg[GLEN], hreg[GLEN];
  float W = 1.f, T = 0.f;
  #pragma unroll
  for (int j = 0; j < GLEN; ++j) {
    const int c = g * GLEN + j;
    const size_t o = ((size_t)bk * NCH + c) * DI + d;
    float wv = __expf(An * sumdB[o]);
    float hv = hN[o * NS + n];
    wreg[j] = wv; hreg[j] = hv;
    T = hv + wv * T;
    W *= wv;
  }
  Wl[g][n] = W; Tl[g][n] = T;
  __syncthreads();
  if (g == 0) {
    float H = 0.f;
    #pragma unroll
    for (int g2 = 0; g2 < GCH; ++g2) {
      float Wv = Wl[g2][n], Tv = Tl[g2][n];
      Hl[g2][n] = H;
      H = Tv + Wv * H;
    }
  }
  __syncthreads();
  float e = Hl[g][n];
  #pragma unroll
  for (int j = 0; j < GLEN; ++j) {
    const int c = g * GLEN + j;
    const size_t o = ((size_t)bk * NCH + c) * DI + d;
    hN[o * NS + n] = e;
    e = hreg[j] + wreg[j] * e;
  }
}

// ---- scan correction (packed fp32): ypl[p] += C . (h0 * exp(An*cum)) -----------
__launch_bounds__(192)
__global__ void scan_corr(const float* __restrict__ xdbl, const float* __restrict__ Alog,
                          const float* __restrict__ dtw, const float* __restrict__ dtb,
                          const float* __restrict__ hin, float* __restrict__ ypl) {
  const int d = threadIdx.x;
  const int ch = blockIdx.x + 1;            // ch=0 has zero entry state
  const int k = blockIdx.y, b = blockIdx.z;
  const int bk = b * KD + k;
  __shared__ float4 Bsh[CLEN * 6];          // per pos: C(q4..7) dt(q8,q9)
  {
    int idx = d;                            // CLEN*6 == 192
    int j = idx / 6, q = idx % 6;
    int p = pos_of(k, ch * CLEN + j);
    Bsh[idx] = *(const float4*)&xdbl[(size_t)(b * LSEQ + p) * XDS + k * 40 + (q + 4) * 4];
  }
  float Al[NS];
  {
    const float4* Ap = (const float4*)&Alog[((size_t)k * DI + d) * NS];
    #pragma unroll
    for (int q = 0; q < 4; ++q) {
      float4 a = Ap[q];
      Al[q*4+0] = a.x; Al[q*4+1] = a.y; Al[q*4+2] = a.z; Al[q*4+3] = a.w;
    }
  }
  const bool geo = geo_check(Al);
  const float An0 = -__expf(Al[0]);
  float w[RK];
  #pragma unroll
  for (int r = 0; r < RK; ++r) w[r] = dtw[((size_t)k * DI + d) * RK + r];
  const float bsv = dtb[k * DI + d];
  v2f w2[3];
  w2[0] = mkv2(w[0], w[1]); w2[1] = mkv2(w[2], w[3]); w2[2] = mkv2(w[4], w[5]);

  v2f g2[8];                                // entry state h0
  {
    const size_t o = ((size_t)bk * NCH + ch) * DI + d;
    const float4* Hp = (const float4*)&hin[o * NS];
    #pragma unroll
    for (int q = 0; q < 4; ++q) {
      float4 v = Hp[q];
      g2[2*q]   = mkv2(v.x, v.y);
      g2[2*q+1] = mkv2(v.z, v.w);
    }
  }
  __syncthreads();
  const int l0 = ch * CLEN;
  const int p0 = pos_of(k, l0);
  const long pstride = (long)pos_step(k) * DI;
  float* youtp = ypl + ((size_t)bk * LSEQ + p0) * DI + d;
  float cum = 0.f;
  if (geo) {
    #pragma unroll 2
    for (int j = 0; j < CLEN; ++j) {
      float4 t0 = Bsh[j * 6 + 4], t1 = Bsh[j * 6 + 5];
      cum += softplus_f(dt6p(w2, bsv, t0, t1));
      v2f pw2[8];
      pw8p(__expf(cum * An0), pw2);
      v2f y2 = mkv2(0.f, 0.f);
      #pragma unroll
      for (int q = 0; q < 4; ++q) {
        float4 c4 = Bsh[j * 6 + q];
        y2 = pk_fma(pk_mul(pw2[2*q],   g2[2*q]),   mkv2(c4.x, c4.y), y2);
        y2 = pk_fma(pk_mul(pw2[2*q+1], g2[2*q+1]), mkv2(c4.z, c4.w), y2);
      }
      *youtp += y2.x + y2.y;
      youtp += pstride;
    }
  } else {
    float An[NS];
    #pragma unroll
    for (int n = 0; n < NS; ++n) An[n] = -__expf(Al[n]);
    #pragma unroll 1
    for (int j = 0; j < CLEN; ++j) {
      float4 t0 = Bsh[j * 6 + 4], t1 = Bsh[j * 6 + 5];
      cum += softplus_f(dt6(w, bsv, t0, t1));
      float y = 0.f;
      #pragma unroll
      for (int q = 0; q < 4; ++q) {
        float4 c4 = Bsh[j * 6 + q];
        y += (__expf(An[q*4+0] * cum) * g2[2*q].x)   * c4.x;
        y += (__expf(An[q*4+1] * cum) * g2[2*q].y)   * c4.y;
        y += (__expf(An[q*4+2] * cum) * g2[2*q+1].x) * c4.z;
        y += (__expf(An[q*4+3] * cum) * g2[2*q+1].y) * c4.w;
      }
      *youtp += y;
      youtp += pstride;
    }
  }
}

// -------- 4-plane merge (Ds term) + LayerNorm + SiLU gate ----------------
__launch_bounds__(192)
__global__ void fuse_ln(const float* __restrict__ ypl, const float* __restrict__ xc,
                        const float* __restrict__ Ds, const float* __restrict__ xz,
                        const float* __restrict__ lnw, const float* __restrict__ lnb,
                        float* __restrict__ ymul) {
  const int row = blockIdx.x;           // b*L + p
  const int b = row >> 12;
  const size_t pd = (size_t)row * DI + threadIdx.x;
  const int d = threadIdx.x;
  constexpr size_t PL = (size_t)LSEQ * DI;
  float u = xc[pd];
  float sDs = Ds[d] + Ds[DI + d] + Ds[2 * DI + d] + Ds[3 * DI + d];
  const size_t base = (size_t)(b * KD) * PL + pd - (size_t)b * PL;
  float y = ypl[base] + ypl[base + PL] + ypl[base + 2 * PL] + ypl[base + 3 * PL] + sDs * u;
  float s1 = y, s2 = y * y;
  #pragma unroll
  for (int off = 32; off; off >>= 1) {
    s1 += __shfl_xor(s1, off);
    s2 += __shfl_xor(s2, off);
  }
  __shared__ float r1[3], r2[3];
  int wid = d >> 6;
  if ((d & 63) == 0) { r1[wid] = s1; r2[wid] = s2; }
  __syncthreads();
  float S1 = r1[0] + r1[1] + r1[2];
  float S2 = r2[0] + r2[1] + r2[2];
  float mu = S1 * (1.f / DI);
  float var = S2 * (1.f / DI) - mu * mu;
  float yn = (y - mu) * rsqrtf(var + 1e-5f) * lnw[d] + lnb[d];
  float zv = xz[(size_t)row * (2 * DI) + DI + d];
  float g = zv / (1.f + __expf(-zv));
  ymul[pd] = yn * g;
}

// ---------------- launcher ----------------
extern "C" void kernel_launch(void* const* d_in, const int* in_sizes, int n_in,
                              void* d_out, int out_size, void* d_ws, size_t ws_size,
                              hipStream_t stream) {
  (void)in_sizes; (void)n_in; (void)out_size; (void)ws_size;
  const float* x          = (const float*)d_in[0];
  const float* in_proj_w  = (const float*)d_in[1];
  const float* conv_w     = (const float*)d_in[2];
  const float* conv_b     = (const float*)d_in[3];
  const float* x_proj_w   = (const float*)d_in[4];
  const float* dt_w       = (const float*)d_in[5];
  const float* dt_b       = (const float*)d_in[6];
  const float* A_logs     = (const float*)d_in[7];
  const float* Ds         = (const float*)d_in[8];
  const float* ln_w       = (const float*)d_in[9];
  const float* ln_b       = (const float*)d_in[10];
  const float* out_proj_w = (const float*)d_in[11];
  float* out = (float*)d_out;
  float* ws  = (float*)d_ws;

  constexpr size_t SZ_XZ    = (size_t)BATCH * LSEQ * 2 * DI;
  constexpr size_t SZ_XC    = (size_t)BATCH * LSEQ * DI;
  constexpr size_t SZ_XD    = (size_t)BATCH * LSEQ * XDS;
  constexpr size_t SZ_HN    = (size_t)BATCH * KD * NCH * DI * NS;   // 25 MB
  constexpr size_t SZ_SUMD  = (size_t)BATCH * KD * NCH * DI;
  constexpr size_t SZ_YPL   = (size_t)BATCH * KD * LSEQ * DI;

  float* xz    = ws;
  float* xc    = xz + SZ_XZ;
  float* xdbl  = xc + SZ_XC;
  float* hN    = xdbl + SZ_XD;
  float* sumd  = hN + SZ_HN;
  float* ypl   = sumd + SZ_SUMD;
  float* WcatT = ypl + SZ_YPL;
  float* inpT  = WcatT + (size_t)DI * XDS;
  float* outpT = inpT + (size_t)DM * 2 * DI;
  float* ymul  = hN;    // hN dead after scan_corr; reuse for LN output

  const int M = BATCH * LSEQ;  // 16384
  const int PREP = DI * XDS + 2 * DI * DM + DM * DI;

  // 0. weight prep (merged)
  prep_weights<<<(PREP + 255) / 256, 256, 0, stream>>>(x_proj_w, in_proj_w, out_proj_w,
                                                       WcatT, inpT, outpT);
  // 1. in_proj
  gemm_nt<2 * DI, DM, 64, 96><<<dim3(6, M / 64), 256, 0, stream>>>(x, inpT, xz, M);
  // 2. depthwise conv + SiLU -> xc
  conv_silu<<<(BATCH * LSEQ * DI) / 256, 256, 0, stream>>>(xz, conv_w, conv_b, xc);
  // 3. x_proj all directions: xdbl[M,160]
  gemm_nt<XDS, DI, 64, 96><<<dim3(3, M / 64), 256, 0, stream>>>(xc, WcatT, xdbl, M);
  // 4. scan phase 1: local scan + y_loc -> planes (packed fp32)
  scan_phase1<<<dim3(NCH, KD, BATCH), 192, 0, stream>>>(xc, xdbl, A_logs, dt_w, dt_b,
                                                        hN, sumd, ypl);
  // 5. fused hierarchical combine (hN -> entry states, in place)
  combine_all<<<dim3(DI, KD, BATCH), 256, 0, stream>>>(hN, sumd, A_logs);
  // 6. correction: ypl += C . (h0 * exp(An*cumDelta))  (packed fp32)
  scan_corr<<<dim3(NCH - 1, KD, BATCH), 192, 0, stream>>>(xdbl, A_logs, dt_w, dt_b,
                                                          hN, ypl);
  // 7. merge 4 planes + LN + gate -> ymul (aliases hN)
  fuse_ln<<<M, DI, 0, stream>>>(ypl, xc, Ds, xz, ln_w, ln_b, ymul);
  // 8. out_proj
  gemm_nt<DM, DI, 64, 96><<<dim3(2, M / 64), 256, 0, stream>>>(ymul, outpT, out, M);
}